// Round 3
// baseline (1030.916 us; speedup 1.0000x reference)
//
#include <hip/hip_runtime.h>
#include <hip/hip_bf16.h>
#include <stdint.h>

// TermEncoder GAT: N=50000, E=800000, D=128, H=2, C=128, HC=256
// R3: output written as f32 (reference output dtype is float32; r2's bf16
// output write explains the 0.5586 absmax exactly). Inputs: on-device dtype
// sniff (f32 vs bf16 floats, int32 vs int64 edge index) -> canonical f32.
// GEMMs: mfma_f32_16x16x32_bf16 with hi/lo split (3 MFMAs/k-step, ~fp32 acc).
#define HC 256
#define NEG_SLOPE 0.2f
#define SOFTMAX_EPS 1e-16f

typedef __bf16 bf16x8 __attribute__((ext_vector_type(8)));
typedef float floatx4 __attribute__((ext_vector_type(4)));

// ---------------------------------------------------------------------------
// dtype sniffing: flags[0]=1 if float tensors are bf16, flags[1]=1 if edge
// index is int64. x ~ N(0,1): as bf16 the low-16 exponent field of each u32
// concentrates in [90,135] (~100%); as f32 those bits are mantissa (~18%).
// int64 edge indices (< 2^31) have all-zero odd u32 words.
// ---------------------------------------------------------------------------
__global__ void detect_kernel(const uint32_t* __restrict__ xw,
                              const uint32_t* __restrict__ ew,
                              int* __restrict__ flags) {
    __shared__ int cnt_bf16, cnt_odd_nz;
    const int t = threadIdx.x;
    if (t == 0) { cnt_bf16 = 0; cnt_odd_nz = 0; }
    __syncthreads();
    uint32_t w = xw[t];
    uint32_t ef = ((w & 0xFFFFu) >> 7) & 0xFFu;
    if (ef >= 90u && ef <= 135u) atomicAdd(&cnt_bf16, 1);
    if (t < 64) {
        if (ew[2 * t + 1] != 0u) atomicAdd(&cnt_odd_nz, 1);
    }
    __syncthreads();
    if (t == 0) {
        flags[0] = (cnt_bf16 > 192) ? 1 : 0;   // float-is-bf16
        flags[1] = (cnt_odd_nz == 0) ? 1 : 0;  // index-is-int64
    }
}

__global__ void convert_kernel(const void* __restrict__ in, float* __restrict__ out,
                               int n, const int* __restrict__ flags) {
    const int is_bf16 = flags[0];
    int i = blockIdx.x * blockDim.x + threadIdx.x;
    if (i < n)
        out[i] = is_bf16 ? (float)((const __hip_bfloat16*)in)[i] : ((const float*)in)[i];
}

// ---------------------------------------------------------------------------
// GEMM: C[M,O] = A[M,K] @ B[O,K]^T (+bias). A,B f32; split into bf16 hi+lo,
// 3 MFMAs per 32-wide k-step (drop lo*lo, ~2^-18 rel err). 4 waves/block,
// each wave: 16 rows x O cols via mfma_f32_16x16x32_bf16.
// A-operand layout: A[m=lane&15][k=(lane>>4)*8+j]; B likewise on columns;
// C/D: col=lane&15, row=(lane>>4)*4+reg  [learn_hip m89/m91].
// ---------------------------------------------------------------------------
__device__ __forceinline__ void split8(const float* __restrict__ p, bf16x8& hi, bf16x8& lo) {
    float4 v0 = *(const float4*)p;
    float4 v1 = *(const float4*)(p + 4);
    float vv[8] = {v0.x, v0.y, v0.z, v0.w, v1.x, v1.y, v1.z, v1.w};
#pragma unroll
    for (int j = 0; j < 8; j++) {
        __bf16 h = (__bf16)vv[j];
        hi[j] = h;
        lo[j] = (__bf16)(vv[j] - (float)h);
    }
}

template <int OTILES, bool BIAS>
__global__ __launch_bounds__(256) void gemm_bt(const float* __restrict__ A,
                                               const float* __restrict__ B,
                                               const float* __restrict__ bias,
                                               float* __restrict__ C,
                                               int M, int K) {
    const int O = OTILES * 16;
    const int lane = threadIdx.x & 63;
    const int wave = threadIdx.x >> 6;
    const int mbase = blockIdx.x * 64 + wave * 16;
    const int l15 = lane & 15;
    const int kq = (lane >> 4) * 8;
    const int arow = min(mbase + l15, M - 1);

    floatx4 acc[OTILES];
#pragma unroll
    for (int t = 0; t < OTILES; t++) acc[t] = (floatx4){0.f, 0.f, 0.f, 0.f};

    for (int k0 = 0; k0 < K; k0 += 32) {
        bf16x8 ah, alo;
        split8(A + (size_t)arow * K + k0 + kq, ah, alo);
#pragma unroll
        for (int t = 0; t < OTILES; t++) {
            bf16x8 bh, blo;
            split8(B + (size_t)(t * 16 + l15) * K + k0 + kq, bh, blo);
            acc[t] = __builtin_amdgcn_mfma_f32_16x16x32_bf16(ah, bh, acc[t], 0, 0, 0);
            acc[t] = __builtin_amdgcn_mfma_f32_16x16x32_bf16(alo, bh, acc[t], 0, 0, 0);
            acc[t] = __builtin_amdgcn_mfma_f32_16x16x32_bf16(ah, blo, acc[t], 0, 0, 0);
        }
    }

    const int rbase = mbase + ((lane >> 4) << 2);
#pragma unroll
    for (int t = 0; t < OTILES; t++) {
#pragma unroll
        for (int r = 0; r < 4; r++) {
            int grow = rbase + r;
            if (grow < M) {
                int gcol = t * 16 + l15;
                float v = acc[t][r];
                if constexpr (BIAS) v += bias[gcol];
                C[(size_t)grow * O + gcol] = v;
            }
        }
    }
}

// ---------------------------------------------------------------------------
// alpha_{l,r}[n,h] = sum_c xl[n,h,c] * att_{l,r}[h,c]; one block per node.
// ---------------------------------------------------------------------------
__global__ __launch_bounds__(256) void alpha_kernel(const float* __restrict__ xl,
                                                    const float* __restrict__ att_l,
                                                    const float* __restrict__ att_r,
                                                    float* __restrict__ al,
                                                    float* __restrict__ ar) {
    const int n = blockIdx.x;
    const int t = threadIdx.x;
    float v = xl[(size_t)n * HC + t];
    __shared__ float sl[256], sr[256];
    sl[t] = v * att_l[t];
    sr[t] = v * att_r[t];
    __syncthreads();
    for (int s = 64; s > 0; s >>= 1) {
        if ((t & 127) < s) { sl[t] += sl[t + s]; sr[t] += sr[t + s]; }
        __syncthreads();
    }
    if ((t & 127) == 0) {
        int h = t >> 7;
        al[n * 2 + h] = sl[t];
        ar[n * 2 + h] = sr[t];
    }
}

// ---------------------------------------------------------------------------
// CSR build (edge accessors switch on int32/int64 storage flag)
// ---------------------------------------------------------------------------
__device__ __forceinline__ int edge_src(const int* ei, int E, int e, int is64) {
    return is64 ? ei[2 * (size_t)e] : ei[e];
}
__device__ __forceinline__ int edge_dst(const int* ei, int E, int e, int is64) {
    return is64 ? ei[2 * (size_t)E + 2 * (size_t)e] : ei[(size_t)E + e];
}

__global__ void count_kernel(const int* __restrict__ ei, int E,
                             const int* __restrict__ flags, int* __restrict__ counts) {
    int e = blockIdx.x * blockDim.x + threadIdx.x;
    if (e < E) atomicAdd(&counts[edge_dst(ei, E, e, flags[1])], 1);
}

__global__ __launch_bounds__(1024) void scan_kernel(const int* __restrict__ counts,
                                                    int* __restrict__ row_ptr,
                                                    int* __restrict__ fill, int N) {
    __shared__ int tmp[1024];
    __shared__ int s_run;
    const int t = threadIdx.x;
    if (t == 0) s_run = 0;
    __syncthreads();
    for (int base = 0; base < N; base += 1024) {
        int v = (base + t < N) ? counts[base + t] : 0;
        tmp[t] = v;
        __syncthreads();
        for (int off = 1; off < 1024; off <<= 1) {
            int x = (t >= off) ? tmp[t - off] : 0;
            __syncthreads();
            tmp[t] += x;
            __syncthreads();
        }
        int run = s_run;
        if (base + t < N) {
            int e0 = run + tmp[t] - v;   // exclusive
            row_ptr[base + t] = e0;
            fill[base + t] = e0;
        }
        int total = tmp[1023];
        __syncthreads();
        if (t == 0) s_run = run + total;
        __syncthreads();
    }
    if (t == 0) row_ptr[N] = s_run;
}

__global__ void scatter_kernel(const int* __restrict__ ei, int E,
                               const int* __restrict__ flags,
                               int* __restrict__ fill, int* __restrict__ esrc) {
    int e = blockIdx.x * blockDim.x + threadIdx.x;
    if (e < E) {
        int is64 = flags[1];
        int s = edge_src(ei, E, e, is64);
        int d = edge_dst(ei, E, e, is64);
        int pos = atomicAdd(&fill[d], 1);
        esrc[pos] = s;
    }
}

// ---------------------------------------------------------------------------
// Segment softmax + weighted aggregation (+fused relu). One block per dst.
// ---------------------------------------------------------------------------
__device__ __forceinline__ float block_reduce_max(float v, float* sred, int t) {
    sred[t] = v;
    __syncthreads();
    for (int s = 128; s > 0; s >>= 1) {
        if (t < s) sred[t] = fmaxf(sred[t], sred[t + s]);
        __syncthreads();
    }
    float r = sred[0];
    __syncthreads();
    return r;
}
__device__ __forceinline__ float block_reduce_sum(float v, float* sred, int t) {
    sred[t] = v;
    __syncthreads();
    for (int s = 128; s > 0; s >>= 1) {
        if (t < s) sred[t] += sred[t + s];
        __syncthreads();
    }
    float r = sred[0];
    __syncthreads();
    return r;
}

__global__ __launch_bounds__(256) void agg_kernel(const float* __restrict__ xl,
                                                  const float* __restrict__ al,
                                                  const float* __restrict__ ar,
                                                  const int* __restrict__ row_ptr,
                                                  const int* __restrict__ esrc,
                                                  float* __restrict__ out) {
    const int i = blockIdx.x;
    const int t = threadIdx.x;
    const int start = row_ptr[i];
    const int end = row_ptr[i + 1];
    if (start == end) {
        out[(size_t)i * HC + t] = 0.f;
        return;
    }
    const float ar0 = ar[i * 2], ar1 = ar[i * 2 + 1];
    __shared__ float sred[256];

    float m0 = -INFINITY, m1 = -INFINITY;
    for (int j = start + t; j < end; j += 256) {
        int s = esrc[j];
        float e0 = al[s * 2] + ar0;     e0 = e0 > 0.f ? e0 : NEG_SLOPE * e0;
        float e1 = al[s * 2 + 1] + ar1; e1 = e1 > 0.f ? e1 : NEG_SLOPE * e1;
        m0 = fmaxf(m0, e0);
        m1 = fmaxf(m1, e1);
    }
    const float M0 = block_reduce_max(m0, sred, t);
    const float M1 = block_reduce_max(m1, sred, t);

    float s0 = 0.f, s1 = 0.f;
    for (int j = start + t; j < end; j += 256) {
        int s = esrc[j];
        float e0 = al[s * 2] + ar0;     e0 = e0 > 0.f ? e0 : NEG_SLOPE * e0;
        float e1 = al[s * 2 + 1] + ar1; e1 = e1 > 0.f ? e1 : NEG_SLOPE * e1;
        s0 += __expf(e0 - M0);
        s1 += __expf(e1 - M1);
    }
    const float inv0 = 1.f / (block_reduce_sum(s0, sred, t) + SOFTMAX_EPS);
    const float inv1 = 1.f / (block_reduce_sum(s1, sred, t) + SOFTMAX_EPS);

    __shared__ int csrc[128];
    __shared__ float cw[256];
    const int h = t >> 7;
    float acc = 0.f;
    for (int base = start; base < end; base += 128) {
        int n = min(128, end - base);
        if (t < n) {
            int s = esrc[base + t];
            csrc[t] = s;
            float e0 = al[s * 2] + ar0;     e0 = e0 > 0.f ? e0 : NEG_SLOPE * e0;
            float e1 = al[s * 2 + 1] + ar1; e1 = e1 > 0.f ? e1 : NEG_SLOPE * e1;
            cw[t * 2] = __expf(e0 - M0) * inv0;
            cw[t * 2 + 1] = __expf(e1 - M1) * inv1;
        }
        __syncthreads();
        for (int jj = 0; jj < n; jj++)
            acc += cw[jj * 2 + h] * xl[(size_t)csrc[jj] * HC + t];
        __syncthreads();
    }
    out[(size_t)i * HC + t] = fmaxf(acc, 0.f);
}

// ---------------------------------------------------------------------------
extern "C" void kernel_launch(void* const* d_in, const int* in_sizes, int n_in,
                              void* d_out, int out_size, void* d_ws, size_t ws_size,
                              hipStream_t stream) {
    const int D = 128;
    const int N = in_sizes[0] / D;   // 50000
    const int E = in_sizes[1] / 2;   // 800000
    const int* ei = (const int*)d_in[1];

    char* w = (char*)d_ws;
    auto alloc = [&](size_t bytes) {
        void* p = w;
        w += (bytes + 255) & ~(size_t)255;
        return p;
    };
    int*   flags   = (int*)  alloc(256);
    float* xf      = (float*)alloc((size_t)N * D * 4);
    float* Wf1     = (float*)alloc((size_t)in_sizes[2] * 4);
    float* atl1    = (float*)alloc((size_t)in_sizes[3] * 4);
    float* atr1    = (float*)alloc((size_t)in_sizes[4] * 4);
    float* Wf2     = (float*)alloc((size_t)in_sizes[5] * 4);
    float* atl2    = (float*)alloc((size_t)in_sizes[6] * 4);
    float* atr2    = (float*)alloc((size_t)in_sizes[7] * 4);
    float* Wfp1    = (float*)alloc((size_t)in_sizes[8] * 4);
    float* bfp1    = (float*)alloc((size_t)in_sizes[9] * 4);
    float* Wfp2    = (float*)alloc((size_t)in_sizes[10] * 4);
    float* bfp2    = (float*)alloc((size_t)in_sizes[11] * 4);
    float* xl      = (float*)alloc((size_t)N * HC * 4);     // 51.2 MB
    float* agg     = (float*)alloc((size_t)N * HC * 4);     // 51.2 MB
    float* al      = (float*)alloc((size_t)N * 2 * 4);
    float* ar      = (float*)alloc((size_t)N * 2 * 4);
    int*   counts  = (int*)  alloc((size_t)N * 4);
    int*   row_ptr = (int*)  alloc((size_t)(N + 1) * 4);
    int*   fill    = (int*)  alloc((size_t)N * 4);
    int*   esrc    = (int*)  alloc((size_t)E * 4);

    const int EB = (E + 255) / 256;
    const int GM = (N + 63) / 64;

    // 0. dtype sniff
    detect_kernel<<<1, 256, 0, stream>>>((const uint32_t*)d_in[0], (const uint32_t*)d_in[1], flags);

    // 1. canonicalize float inputs to f32
    {
        float* dsts[11] = {xf, Wf1, atl1, atr1, Wf2, atl2, atr2, Wfp1, bfp1, Wfp2, bfp2};
        int    idxs[11] = {0, 2, 3, 4, 5, 6, 7, 8, 9, 10, 11};
        for (int i = 0; i < 11; i++) {
            int n = in_sizes[idxs[i]];
            convert_kernel<<<(n + 255) / 256, 256, 0, stream>>>(d_in[idxs[i]], dsts[i], n, flags);
        }
    }

    // 2. CSR build
    hipMemsetAsync(counts, 0, (size_t)N * 4, stream);
    count_kernel<<<EB, 256, 0, stream>>>(ei, E, flags, counts);
    scan_kernel<<<1, 1024, 0, stream>>>(counts, row_ptr, fill, N);
    scatter_kernel<<<EB, 256, 0, stream>>>(ei, E, flags, fill, esrc);

    // 3. GAT layer 1
    gemm_bt<16, false><<<GM, 256, 0, stream>>>(xf, Wf1, nullptr, xl, N, 128);
    alpha_kernel<<<N, 256, 0, stream>>>(xl, atl1, atr1, al, ar);
    agg_kernel<<<N, 256, 0, stream>>>(xl, al, ar, row_ptr, esrc, agg);

    // 4. GAT layer 2
    gemm_bt<16, false><<<GM, 256, 0, stream>>>(agg, Wf2, nullptr, xl, N, 256);
    alpha_kernel<<<N, 256, 0, stream>>>(xl, atl2, atr2, al, ar);
    agg_kernel<<<N, 256, 0, stream>>>(xl, al, ar, row_ptr, esrc, agg);

    // 5. projections: p1 = agg@Wp1^T + bp1 (reuse xf as [N,128] f32)
    gemm_bt<8, true><<<GM, 256, 0, stream>>>(agg, Wfp1, bfp1, xf, N, 256);
    // out = p1@Wp2^T + bp2 -> f32 d_out (reference output dtype is float32)
    gemm_bt<8, true><<<GM, 256, 0, stream>>>(xf, Wfp2, bfp2, (float*)d_out, N, 128);
}

// Round 4
// 807.378 us; speedup vs baseline: 1.2769x; 1.2769x over previous
//
#include <hip/hip_runtime.h>
#include <hip/hip_bf16.h>
#include <stdint.h>

// TermEncoder GAT: N=50000, E=800000, D=128, H=2, C=128, HC=256
// R4: perf pass. Pre-split bf16 hi/lo operands (no split8 in GEMM inner loop),
// alpha fused into GEMM epilogue, agg split into thread-per-node softmax
// weights + wave-per-edge float4 gather, 3-kernel scan, fused converts.
#define HC 256
#define NEG_SLOPE 0.2f
#define SOFTMAX_EPS 1e-16f

typedef __bf16 bf16x8 __attribute__((ext_vector_type(8)));
typedef float floatx4 __attribute__((ext_vector_type(4)));

// ---------------------------------------------------------------------------
// dtype sniffing (kept from r3 — r2/r3 evidence says floats are f32, but stay
// robust): flags[0]=float-is-bf16, flags[1]=edge-index-is-int64.
// ---------------------------------------------------------------------------
__global__ void detect_kernel(const uint32_t* __restrict__ xw,
                              const uint32_t* __restrict__ ew,
                              int* __restrict__ flags) {
    __shared__ int cnt_bf16, cnt_odd_nz;
    const int t = threadIdx.x;
    if (t == 0) { cnt_bf16 = 0; cnt_odd_nz = 0; }
    __syncthreads();
    uint32_t w = xw[t];
    uint32_t ef = ((w & 0xFFFFu) >> 7) & 0xFFu;
    if (ef >= 90u && ef <= 135u) atomicAdd(&cnt_bf16, 1);
    if (t < 64 && ew[2 * t + 1] != 0u) atomicAdd(&cnt_odd_nz, 1);
    __syncthreads();
    if (t == 0) {
        flags[0] = (cnt_bf16 > 192) ? 1 : 0;
        flags[1] = (cnt_odd_nz == 0) ? 1 : 0;
    }
}

__device__ __forceinline__ float in_load(const void* p, int i, int is_bf16) {
    return is_bf16 ? (float)((const __bf16*)p)[i] : ((const float*)p)[i];
}

// six small f32 tensors (att_l1, att_r1, att_l2, att_r2, bp1, bp2) in one launch
__global__ void conv_small_kernel(const void* a0, float* o0, int n0,
                                  const void* a1, float* o1, int n1,
                                  const void* a2, float* o2, int n2,
                                  const void* a3, float* o3, int n3,
                                  const void* a4, float* o4, int n4,
                                  const void* a5, float* o5, int n5,
                                  const int* __restrict__ flags) {
    const int t = threadIdx.x;
    const int fb = flags[0];
    if (t < n0) o0[t] = in_load(a0, t, fb);
    if (t < n1) o1[t] = in_load(a1, t, fb);
    if (t < n2) o2[t] = in_load(a2, t, fb);
    if (t < n3) o3[t] = in_load(a3, t, fb);
    if (t < n4) o4[t] = in_load(a4, t, fb);
    if (t < n5) o5[t] = in_load(a5, t, fb);
}

// split one tensor into bf16 hi/lo
__global__ void split_kernel(const void* __restrict__ in, __bf16* __restrict__ hi,
                             __bf16* __restrict__ lo, int n, const int* __restrict__ flags) {
    int i = blockIdx.x * blockDim.x + threadIdx.x;
    if (i >= n) return;
    float v = in_load(in, i, flags[0]);
    __bf16 h = (__bf16)v;
    hi[i] = h;
    lo[i] = (__bf16)(v - (float)h);
}

// split the 4 weight matrices in one launch
__global__ void split4_kernel(const void* i0, __bf16* h0, __bf16* l0, int n0,
                              const void* i1, __bf16* h1, __bf16* l1, int n1,
                              const void* i2, __bf16* h2, __bf16* l2, int n2,
                              const void* i3, __bf16* h3, __bf16* l3, int n3,
                              const int* __restrict__ flags) {
    int idx = blockIdx.x * blockDim.x + threadIdx.x;
    const void* in;
    __bf16 *ph, *pl;
    int off = idx;
    if (off < n0)      { in = i0; ph = h0; pl = l0; }
    else if ((off -= n0) < n1) { in = i1; ph = h1; pl = l1; }
    else if ((off -= n1) < n2) { in = i2; ph = h2; pl = l2; }
    else if ((off -= n2) < n3) { in = i3; ph = h3; pl = l3; }
    else return;
    float v = in_load(in, off, flags[0]);
    __bf16 h = (__bf16)v;
    ph[off] = h;
    pl[off] = (__bf16)(v - (float)h);
}

// ---------------------------------------------------------------------------
// GEMM: C[M,O] = A[M,K]@B[O,K]^T (+bias), A/B pre-split bf16 hi/lo.
// 3 MFMAs/k-step (ah*bh + al*bh + ah*bl). 4 waves/block, 16 rows/wave.
// ALPHA: fused per-row, per-head dot with att_l/att_r (shfl-reduce over l15).
// SPLITOUT: emit hi/lo bf16 (next GEMM's A); else f32.
// ---------------------------------------------------------------------------
template <int OTILES, bool BIAS, bool ALPHA, bool SPLITOUT>
__global__ __launch_bounds__(256) void gemm_bt(
    const __bf16* __restrict__ Ahi, const __bf16* __restrict__ Alo,
    const __bf16* __restrict__ Bhi, const __bf16* __restrict__ Blo,
    const float* __restrict__ bias,
    float* __restrict__ C, __bf16* __restrict__ Chi, __bf16* __restrict__ Clo,
    const float* __restrict__ attl, const float* __restrict__ attr,
    float* __restrict__ al, float* __restrict__ ar,
    int M, int K) {
    const int O = OTILES * 16;
    const int lane = threadIdx.x & 63;
    const int wave = threadIdx.x >> 6;
    const int mbase = blockIdx.x * 64 + wave * 16;
    const int l15 = lane & 15;
    const int kq = (lane >> 4) * 8;
    const int arow = min(mbase + l15, M - 1);

    floatx4 acc[OTILES];
#pragma unroll
    for (int t = 0; t < OTILES; t++) acc[t] = (floatx4){0.f, 0.f, 0.f, 0.f};

    for (int k0 = 0; k0 < K; k0 += 32) {
        const size_t abase = (size_t)arow * K + k0 + kq;
        bf16x8 ah = *(const bf16x8*)(Ahi + abase);
        bf16x8 alo_ = *(const bf16x8*)(Alo + abase);
#pragma unroll
        for (int t = 0; t < OTILES; t++) {
            const size_t bbase = (size_t)(t * 16 + l15) * K + k0 + kq;
            bf16x8 bh = *(const bf16x8*)(Bhi + bbase);
            bf16x8 bl = *(const bf16x8*)(Blo + bbase);
            acc[t] = __builtin_amdgcn_mfma_f32_16x16x32_bf16(ah, bh, acc[t], 0, 0, 0);
            acc[t] = __builtin_amdgcn_mfma_f32_16x16x32_bf16(alo_, bh, acc[t], 0, 0, 0);
            acc[t] = __builtin_amdgcn_mfma_f32_16x16x32_bf16(ah, bl, acc[t], 0, 0, 0);
        }
    }

    // C/D layout: col = lane&15, row = (lane>>4)*4 + reg  [m89/m91]
    const int rbase = mbase + ((lane >> 4) << 2);
    float aL[2][4] = {{0.f}}, aR[2][4] = {{0.f}};
#pragma unroll
    for (int t = 0; t < OTILES; t++) {
        const int gcol = t * 16 + l15;
        float atlv = 0.f, atrv = 0.f;
        if constexpr (ALPHA) { atlv = attl[gcol]; atrv = attr[gcol]; }
        const int hh = (OTILES == 16) ? (t >> 3) : 0;
#pragma unroll
        for (int r = 0; r < 4; r++) {
            float v = acc[t][r];
            if constexpr (BIAS) v += bias[gcol];
            if constexpr (ALPHA) { aL[hh][r] += v * atlv; aR[hh][r] += v * atrv; }
            int grow = rbase + r;
            if (grow < M) {
                if constexpr (SPLITOUT) {
                    __bf16 h = (__bf16)v;
                    Chi[(size_t)grow * O + gcol] = h;
                    Clo[(size_t)grow * O + gcol] = (__bf16)(v - (float)h);
                } else {
                    C[(size_t)grow * O + gcol] = v;
                }
            }
        }
    }

    if constexpr (ALPHA) {
#pragma unroll
        for (int hh = 0; hh < 2; hh++)
#pragma unroll
            for (int r = 0; r < 4; r++) {
                float vl = aL[hh][r], vr = aR[hh][r];
                vl += __shfl_xor(vl, 1); vl += __shfl_xor(vl, 2);
                vl += __shfl_xor(vl, 4); vl += __shfl_xor(vl, 8);
                vr += __shfl_xor(vr, 1); vr += __shfl_xor(vr, 2);
                vr += __shfl_xor(vr, 4); vr += __shfl_xor(vr, 8);
                aL[hh][r] = vl; aR[hh][r] = vr;
            }
        if (l15 == 0) {
#pragma unroll
            for (int r = 0; r < 4; r++) {
                int grow = rbase + r;
                if (grow < M) {
                    al[2 * grow] = aL[0][r];
                    al[2 * grow + 1] = aL[1][r];
                    ar[2 * grow] = aR[0][r];
                    ar[2 * grow + 1] = aR[1][r];
                }
            }
        }
    }
}

// ---------------------------------------------------------------------------
// CSR build
// ---------------------------------------------------------------------------
__device__ __forceinline__ int edge_src(const int* ei, int E, int e, int is64) {
    return is64 ? ei[2 * (size_t)e] : ei[e];
}
__device__ __forceinline__ int edge_dst(const int* ei, int E, int e, int is64) {
    return is64 ? ei[2 * (size_t)E + 2 * (size_t)e] : ei[(size_t)E + e];
}

__global__ void count_kernel(const int* __restrict__ ei, int E,
                             const int* __restrict__ flags, int* __restrict__ counts) {
    int e = blockIdx.x * blockDim.x + threadIdx.x;
    if (e < E) atomicAdd(&counts[edge_dst(ei, E, e, flags[1])], 1);
}

__global__ __launch_bounds__(1024) void scan1_kernel(const int* __restrict__ counts,
                                                     int* __restrict__ incl,
                                                     int* __restrict__ bsum, int N) {
    __shared__ int tmp[1024];
    const int t = threadIdx.x;
    const int i = blockIdx.x * 1024 + t;
    int v = (i < N) ? counts[i] : 0;
    tmp[t] = v;
    __syncthreads();
    for (int off = 1; off < 1024; off <<= 1) {
        int x = (t >= off) ? tmp[t - off] : 0;
        __syncthreads();
        tmp[t] += x;
        __syncthreads();
    }
    if (i < N) incl[i] = tmp[t];
    if (t == 1023) bsum[blockIdx.x] = tmp[1023];
}

__global__ void scan2_kernel(const int* __restrict__ bsum, int* __restrict__ boffs,
                             int nb, int* __restrict__ row_ptr, int N) {
    if (threadIdx.x == 0) {
        int run = 0;
        for (int b = 0; b < nb; b++) { boffs[b] = run; run += bsum[b]; }
        row_ptr[N] = run;
    }
}

__global__ void scan3_kernel(const int* __restrict__ incl, const int* __restrict__ counts,
                             const int* __restrict__ boffs, int* __restrict__ row_ptr,
                             int* __restrict__ fill, int N) {
    int i = blockIdx.x * blockDim.x + threadIdx.x;
    if (i < N) {
        int v = boffs[i >> 10] + incl[i] - counts[i];  // exclusive prefix
        row_ptr[i] = v;
        fill[i] = v;
    }
}

__global__ void scatter_kernel(const int* __restrict__ ei, int E,
                               const int* __restrict__ flags,
                               int* __restrict__ fill, int* __restrict__ esrc) {
    int e = blockIdx.x * blockDim.x + threadIdx.x;
    if (e < E) {
        int is64 = flags[1];
        int s = edge_src(ei, E, e, is64);
        int d = edge_dst(ei, E, e, is64);
        int pos = atomicAdd(&fill[d], 1);
        esrc[pos] = s;
    }
}

// ---------------------------------------------------------------------------
// Per-node softmax weights (thread per node; avg degree 16).
// Writes normalized per-edge weights cw[j][h] in CSR order.
// ---------------------------------------------------------------------------
__global__ void attw_kernel(const float* __restrict__ al, const float* __restrict__ ar,
                            const int* __restrict__ row_ptr, const int* __restrict__ esrc,
                            float* __restrict__ cw, int N) {
    int i = blockIdx.x * blockDim.x + threadIdx.x;
    if (i >= N) return;
    const int s0 = row_ptr[i], e0 = row_ptr[i + 1];
    if (s0 == e0) return;
    const float ar0 = ar[2 * i], ar1 = ar[2 * i + 1];
    float m0 = -INFINITY, m1 = -INFINITY;
    for (int j = s0; j < e0; j++) {
        int s = esrc[j];
        float2 av = *(const float2*)(al + 2 * s);
        float x0 = av.x + ar0; x0 = x0 > 0.f ? x0 : NEG_SLOPE * x0;
        float x1 = av.y + ar1; x1 = x1 > 0.f ? x1 : NEG_SLOPE * x1;
        cw[2 * j] = x0; cw[2 * j + 1] = x1;
        m0 = fmaxf(m0, x0); m1 = fmaxf(m1, x1);
    }
    float d0 = 0.f, d1 = 0.f;
    for (int j = s0; j < e0; j++) {
        d0 += __expf(cw[2 * j] - m0);
        d1 += __expf(cw[2 * j + 1] - m1);
    }
    const float i0 = 1.f / (d0 + SOFTMAX_EPS);
    const float i1 = 1.f / (d1 + SOFTMAX_EPS);
    for (int j = s0; j < e0; j++) {
        cw[2 * j] = __expf(cw[2 * j] - m0) * i0;
        cw[2 * j + 1] = __expf(cw[2 * j + 1] - m1) * i1;
    }
}

// ---------------------------------------------------------------------------
// Feature aggregation: one block per dst node, wave-per-edge, float4/lane
// covers a full 256-col row in one dwordx4. Epilogue: relu + bf16 hi/lo split.
// ---------------------------------------------------------------------------
__global__ __launch_bounds__(256) void aggf_kernel(const float* __restrict__ xl,
                                                   const float* __restrict__ cw,
                                                   const int* __restrict__ row_ptr,
                                                   const int* __restrict__ esrc,
                                                   __bf16* __restrict__ hhi,
                                                   __bf16* __restrict__ hlo) {
    const int i = blockIdx.x;
    const int t = threadIdx.x;
    const int lane = t & 63;
    const int wave = t >> 6;
    const int s0 = row_ptr[i], e0 = row_ptr[i + 1];
    const int hsel = lane >> 5;          // cols [lane*4 .. lane*4+3] -> head col>>7

    float4 acc = {0.f, 0.f, 0.f, 0.f};
    for (int j = s0 + wave; j < e0; j += 4) {
        int s = esrc[j];
        float w = cw[2 * j + hsel];
        float4 xv = *(const float4*)(xl + (size_t)s * HC + lane * 4);
        acc.x += w * xv.x; acc.y += w * xv.y; acc.z += w * xv.z; acc.w += w * xv.w;
    }

    __shared__ float red[3][256];
    if (wave > 0) *(float4*)&red[wave - 1][lane * 4] = acc;
    __syncthreads();
    if (wave == 0) {
        const int c4 = lane * 4;
        acc.x += red[0][c4] + red[1][c4] + red[2][c4];
        acc.y += red[0][c4 + 1] + red[1][c4 + 1] + red[2][c4 + 1];
        acc.z += red[0][c4 + 2] + red[1][c4 + 2] + red[2][c4 + 2];
        acc.w += red[0][c4 + 3] + red[1][c4 + 3] + red[2][c4 + 3];
        const size_t base = (size_t)i * HC + c4;
        float vv[4] = {acc.x, acc.y, acc.z, acc.w};
#pragma unroll
        for (int c = 0; c < 4; c++) {
            float v = fmaxf(vv[c], 0.f);   // fused relu
            __bf16 h = (__bf16)v;
            hhi[base + c] = h;
            hlo[base + c] = (__bf16)(v - (float)h);
        }
    }
}

// ---------------------------------------------------------------------------
extern "C" void kernel_launch(void* const* d_in, const int* in_sizes, int n_in,
                              void* d_out, int out_size, void* d_ws, size_t ws_size,
                              hipStream_t stream) {
    const int D = 128;
    const int N = in_sizes[0] / D;   // 50000
    const int E = in_sizes[1] / 2;   // 800000
    const int* ei = (const int*)d_in[1];

    char* w = (char*)d_ws;
    auto alloc = [&](size_t bytes) {
        void* p = w;
        w += (bytes + 255) & ~(size_t)255;
        return p;
    };
    int*    flags  = (int*)   alloc(256);
    __bf16* x_hi   = (__bf16*)alloc((size_t)N * D * 2);     // 12.8 MB (reused: p_hi)
    __bf16* x_lo   = (__bf16*)alloc((size_t)N * D * 2);     // 12.8 MB (reused: p_lo)
    __bf16* W1h    = (__bf16*)alloc((size_t)in_sizes[2] * 2);
    __bf16* W1l    = (__bf16*)alloc((size_t)in_sizes[2] * 2);
    __bf16* W2h    = (__bf16*)alloc((size_t)in_sizes[5] * 2);
    __bf16* W2l    = (__bf16*)alloc((size_t)in_sizes[5] * 2);
    __bf16* Wp1h   = (__bf16*)alloc((size_t)in_sizes[8] * 2);
    __bf16* Wp1l   = (__bf16*)alloc((size_t)in_sizes[8] * 2);
    __bf16* Wp2h   = (__bf16*)alloc((size_t)in_sizes[10] * 2);
    __bf16* Wp2l   = (__bf16*)alloc((size_t)in_sizes[10] * 2);
    float*  atl1   = (float*) alloc((size_t)in_sizes[3] * 4);
    float*  atr1   = (float*) alloc((size_t)in_sizes[4] * 4);
    float*  atl2   = (float*) alloc((size_t)in_sizes[6] * 4);
    float*  atr2   = (float*) alloc((size_t)in_sizes[7] * 4);
    float*  bfp1   = (float*) alloc((size_t)in_sizes[9] * 4);
    float*  bfp2   = (float*) alloc((size_t)in_sizes[11] * 4);
    float*  xl     = (float*) alloc((size_t)N * HC * 4);    // 51.2 MB
    __bf16* h_hi   = (__bf16*)alloc((size_t)N * HC * 2);    // 25.6 MB (layer1 out; reused layer2 out)
    __bf16* h_lo   = (__bf16*)alloc((size_t)N * HC * 2);    // 25.6 MB
    float*  al     = (float*) alloc((size_t)N * 2 * 4);
    float*  ar     = (float*) alloc((size_t)N * 2 * 4);
    int*    counts = (int*)   alloc((size_t)N * 4);
    int*    incl   = (int*)   alloc((size_t)N * 4);
    int*    row_ptr= (int*)   alloc((size_t)(N + 1) * 4);
    int*    fill   = (int*)   alloc((size_t)N * 4);
    int*    bsum   = (int*)   alloc(1024);
    int*    boffs  = (int*)   alloc(1024);
    int*    esrc   = (int*)   alloc((size_t)E * 4);
    float*  cw     = (float*) alloc((size_t)E * 2 * 4);     // 6.4 MB

    const int EB = (E + 255) / 256;
    const int GM = (N + 63) / 64;
    const int NB1024 = (N + 1023) / 1024;

    // 0. dtype sniff + input canonicalization (hi/lo splits, f32 smalls)
    detect_kernel<<<1, 256, 0, stream>>>((const uint32_t*)d_in[0], (const uint32_t*)d_in[1], flags);
    conv_small_kernel<<<1, 256, 0, stream>>>(d_in[3], atl1, in_sizes[3],
                                             d_in[4], atr1, in_sizes[4],
                                             d_in[6], atl2, in_sizes[6],
                                             d_in[7], atr2, in_sizes[7],
                                             d_in[9], bfp1, in_sizes[9],
                                             d_in[11], bfp2, in_sizes[11], flags);
    split_kernel<<<(in_sizes[0] + 255) / 256, 256, 0, stream>>>(d_in[0], x_hi, x_lo, in_sizes[0], flags);
    {
        int nt = in_sizes[2] + in_sizes[5] + in_sizes[8] + in_sizes[10];
        split4_kernel<<<(nt + 255) / 256, 256, 0, stream>>>(
            d_in[2], W1h, W1l, in_sizes[2],
            d_in[5], W2h, W2l, in_sizes[5],
            d_in[8], Wp1h, Wp1l, in_sizes[8],
            d_in[10], Wp2h, Wp2l, in_sizes[10], flags);
    }

    // 1. CSR build
    hipMemsetAsync(counts, 0, (size_t)N * 4, stream);
    count_kernel<<<EB, 256, 0, stream>>>(ei, E, flags, counts);
    scan1_kernel<<<NB1024, 1024, 0, stream>>>(counts, incl, bsum, N);
    scan2_kernel<<<1, 64, 0, stream>>>(bsum, boffs, NB1024, row_ptr, N);
    scan3_kernel<<<(N + 255) / 256, 256, 0, stream>>>(incl, counts, boffs, row_ptr, fill, N);
    scatter_kernel<<<EB, 256, 0, stream>>>(ei, E, flags, fill, esrc);

    // 2. GAT layer 1: xl = x@W1^T (alpha fused)
    gemm_bt<16, false, true, false><<<GM, 256, 0, stream>>>(
        x_hi, x_lo, W1h, W1l, nullptr, xl, nullptr, nullptr, atl1, atr1, al, ar, N, 128);
    attw_kernel<<<(N + 255) / 256, 256, 0, stream>>>(al, ar, row_ptr, esrc, cw, N);
    aggf_kernel<<<N, 256, 0, stream>>>(xl, cw, row_ptr, esrc, h_hi, h_lo);

    // 3. GAT layer 2: xl = h1@W2^T (alpha fused); agg overwrites h buffers
    gemm_bt<16, false, true, false><<<GM, 256, 0, stream>>>(
        h_hi, h_lo, W2h, W2l, nullptr, xl, nullptr, nullptr, atl2, atr2, al, ar, N, 256);
    attw_kernel<<<(N + 255) / 256, 256, 0, stream>>>(al, ar, row_ptr, esrc, cw, N);
    aggf_kernel<<<N, 256, 0, stream>>>(xl, cw, row_ptr, esrc, h_hi, h_lo);

    // 4. projections: p = h2@Wp1^T + bp1 (hi/lo out, reusing x buffers)
    gemm_bt<8, true, false, true><<<GM, 256, 0, stream>>>(
        h_hi, h_lo, Wp1h, Wp1l, bfp1, nullptr, x_hi, x_lo, nullptr, nullptr, nullptr, nullptr, N, 256);
    // out = p@Wp2^T + bp2 -> f32 d_out
    gemm_bt<8, true, false, false><<<GM, 256, 0, stream>>>(
        x_hi, x_lo, Wp2h, Wp2l, bfp2, (float*)d_out, nullptr, nullptr, nullptr, nullptr, nullptr, nullptr, N, 128);
}

// Round 5
// 694.452 us; speedup vs baseline: 1.4845x; 1.1626x over previous
//
#include <hip/hip_runtime.h>
#include <hip/hip_bf16.h>
#include <stdint.h>

// TermEncoder GAT: N=50000, E=800000, D=128, H=2, C=128, HC=256
// R5: GEMM restructure. r4 counters: gemm<16> 133us, MfmaUtil 5.7%, VALU 6.6%,
// HBM 7.5% -> latency-bound (34 loads/wave/k-step, waitcnt per t-iter).
// Fix: cols split across waves (16 loads/k-step), batched loads -> one wait
// per k-step, K templated for full unroll. Agg pipeline unchanged.
#define HC 256
#define NEG_SLOPE 0.2f
#define SOFTMAX_EPS 1e-16f

typedef __bf16 bf16x8 __attribute__((ext_vector_type(8)));
typedef float floatx4 __attribute__((ext_vector_type(4)));

// ---------------------------------------------------------------------------
// dtype sniffing: flags[0]=float-is-bf16, flags[1]=edge-index-is-int64.
// ---------------------------------------------------------------------------
__global__ void detect_kernel(const uint32_t* __restrict__ xw,
                              const uint32_t* __restrict__ ew,
                              int* __restrict__ flags) {
    __shared__ int cnt_bf16, cnt_odd_nz;
    const int t = threadIdx.x;
    if (t == 0) { cnt_bf16 = 0; cnt_odd_nz = 0; }
    __syncthreads();
    uint32_t w = xw[t];
    uint32_t ef = ((w & 0xFFFFu) >> 7) & 0xFFu;
    if (ef >= 90u && ef <= 135u) atomicAdd(&cnt_bf16, 1);
    if (t < 64 && ew[2 * t + 1] != 0u) atomicAdd(&cnt_odd_nz, 1);
    __syncthreads();
    if (t == 0) {
        flags[0] = (cnt_bf16 > 192) ? 1 : 0;
        flags[1] = (cnt_odd_nz == 0) ? 1 : 0;
    }
}

__device__ __forceinline__ float in_load(const void* p, int i, int is_bf16) {
    return is_bf16 ? (float)((const __bf16*)p)[i] : ((const float*)p)[i];
}

__global__ void conv_small_kernel(const void* a0, float* o0, int n0,
                                  const void* a1, float* o1, int n1,
                                  const void* a2, float* o2, int n2,
                                  const void* a3, float* o3, int n3,
                                  const void* a4, float* o4, int n4,
                                  const void* a5, float* o5, int n5,
                                  const int* __restrict__ flags) {
    const int t = threadIdx.x;
    const int fb = flags[0];
    if (t < n0) o0[t] = in_load(a0, t, fb);
    if (t < n1) o1[t] = in_load(a1, t, fb);
    if (t < n2) o2[t] = in_load(a2, t, fb);
    if (t < n3) o3[t] = in_load(a3, t, fb);
    if (t < n4) o4[t] = in_load(a4, t, fb);
    if (t < n5) o5[t] = in_load(a5, t, fb);
}

__global__ void split_kernel(const void* __restrict__ in, __bf16* __restrict__ hi,
                             __bf16* __restrict__ lo, int n, const int* __restrict__ flags) {
    int i = blockIdx.x * blockDim.x + threadIdx.x;
    if (i >= n) return;
    float v = in_load(in, i, flags[0]);
    __bf16 h = (__bf16)v;
    hi[i] = h;
    lo[i] = (__bf16)(v - (float)h);
}

__global__ void split4_kernel(const void* i0, __bf16* h0, __bf16* l0, int n0,
                              const void* i1, __bf16* h1, __bf16* l1, int n1,
                              const void* i2, __bf16* h2, __bf16* l2, int n2,
                              const void* i3, __bf16* h3, __bf16* l3, int n3,
                              const int* __restrict__ flags) {
    int idx = blockIdx.x * blockDim.x + threadIdx.x;
    const void* in;
    __bf16 *ph, *pl;
    int off = idx;
    if (off < n0)      { in = i0; ph = h0; pl = l0; }
    else if ((off -= n0) < n1) { in = i1; ph = h1; pl = l1; }
    else if ((off -= n1) < n2) { in = i2; ph = h2; pl = l2; }
    else if ((off -= n2) < n3) { in = i3; ph = h3; pl = l3; }
    else return;
    float v = in_load(in, off, flags[0]);
    __bf16 h = (__bf16)v;
    ph[off] = h;
    pl[off] = (__bf16)(v - (float)h);
}

// ---------------------------------------------------------------------------
// GEMM: C[M,O] = A[M,KTEMP]@B[O,KTEMP]^T (+bias), pre-split bf16 hi/lo.
// Block = 256 thr = 4 waves; block M-tile = 64 rows. Wave w owns O/4 cols
// (TW = OTILES/4 col-tiles), all 4 row-subtiles. Per k-step: 8 A-frag +
// 2*TW B-frag loads batched into registers, then 4*TW*3 MFMAs. K fully
// unrolled (template) so the compiler pipelines loads across k-steps.
// ALPHA (OTILES==16): per-wave head = wave>>1; shfl over l15 + LDS combine.
// ---------------------------------------------------------------------------
template <int KTEMP, int OTILES, bool BIAS, bool ALPHA, bool SPLITOUT>
__global__ __launch_bounds__(256) void gemm_bt(
    const __bf16* __restrict__ Ahi, const __bf16* __restrict__ Alo,
    const __bf16* __restrict__ Bhi, const __bf16* __restrict__ Blo,
    const float* __restrict__ bias,
    float* __restrict__ C, __bf16* __restrict__ Chi, __bf16* __restrict__ Clo,
    const float* __restrict__ attl, const float* __restrict__ attr,
    float* __restrict__ al, float* __restrict__ ar,
    int M) {
    static_assert(!ALPHA || OTILES == 16, "alpha fusion assumes O=256");
    constexpr int TW = OTILES / 4;
    constexpr int O = OTILES * 16;
    const int tid = threadIdx.x;
    const int lane = tid & 63;
    const int wave = tid >> 6;
    const int mbase = blockIdx.x * 64;
    const int l15 = lane & 15;
    const int q = lane >> 4;
    const int kq = q * 8;
    const int wc = wave * TW * 16;      // wave's column base

    int arow[4];
#pragma unroll
    for (int rt = 0; rt < 4; rt++) arow[rt] = min(mbase + rt * 16 + l15, M - 1);

    floatx4 acc[4][TW];
#pragma unroll
    for (int rt = 0; rt < 4; rt++)
#pragma unroll
        for (int tt = 0; tt < TW; tt++) acc[rt][tt] = (floatx4){0.f, 0.f, 0.f, 0.f};

    constexpr int KSTEPS = KTEMP / 32;
#pragma unroll
    for (int ks = 0; ks < KSTEPS; ks++) {
        const int k0 = ks * 32;
        bf16x8 ah[4], alo_[4], bh[TW], bl_[TW];
#pragma unroll
        for (int rt = 0; rt < 4; rt++) {
            const size_t off = (size_t)arow[rt] * KTEMP + k0 + kq;
            ah[rt] = *(const bf16x8*)(Ahi + off);
            alo_[rt] = *(const bf16x8*)(Alo + off);
        }
#pragma unroll
        for (int tt = 0; tt < TW; tt++) {
            const size_t off = (size_t)(wc + tt * 16 + l15) * KTEMP + k0 + kq;
            bh[tt] = *(const bf16x8*)(Bhi + off);
            bl_[tt] = *(const bf16x8*)(Blo + off);
        }
#pragma unroll
        for (int rt = 0; rt < 4; rt++)
#pragma unroll
            for (int tt = 0; tt < TW; tt++) {
                acc[rt][tt] = __builtin_amdgcn_mfma_f32_16x16x32_bf16(ah[rt], bh[tt], acc[rt][tt], 0, 0, 0);
                acc[rt][tt] = __builtin_amdgcn_mfma_f32_16x16x32_bf16(alo_[rt], bh[tt], acc[rt][tt], 0, 0, 0);
                acc[rt][tt] = __builtin_amdgcn_mfma_f32_16x16x32_bf16(ah[rt], bl_[tt], acc[rt][tt], 0, 0, 0);
            }
    }

    // C/D layout: col = lane&15, row(in 16x16 tile) = q*4 + reg  [m89/m91]
    float aLp[4][4], aRp[4][4];
    if constexpr (ALPHA) {
#pragma unroll
        for (int rt = 0; rt < 4; rt++)
#pragma unroll
            for (int r = 0; r < 4; r++) { aLp[rt][r] = 0.f; aRp[rt][r] = 0.f; }
    }

#pragma unroll
    for (int rt = 0; rt < 4; rt++) {
        const int rb = mbase + rt * 16 + q * 4;
#pragma unroll
        for (int tt = 0; tt < TW; tt++) {
            const int gcol = wc + tt * 16 + l15;
            float atlv = 0.f, atrv = 0.f;
            if constexpr (ALPHA) { atlv = attl[gcol]; atrv = attr[gcol]; }
#pragma unroll
            for (int r = 0; r < 4; r++) {
                float v = acc[rt][tt][r];
                if constexpr (BIAS) v += bias[gcol];
                if constexpr (ALPHA) { aLp[rt][r] += v * atlv; aRp[rt][r] += v * atrv; }
                const int grow = rb + r;
                if (grow < M) {
                    if constexpr (SPLITOUT) {
                        __bf16 h = (__bf16)v;
                        Chi[(size_t)grow * O + gcol] = h;
                        Clo[(size_t)grow * O + gcol] = (__bf16)(v - (float)h);
                    } else {
                        C[(size_t)grow * O + gcol] = v;
                    }
                }
            }
        }
    }

    if constexpr (ALPHA) {
        __shared__ float sAL[4][64], sAR[4][64];
#pragma unroll
        for (int rt = 0; rt < 4; rt++)
#pragma unroll
            for (int r = 0; r < 4; r++) {
                float vl = aLp[rt][r], vr = aRp[rt][r];
                vl += __shfl_xor(vl, 1); vl += __shfl_xor(vl, 2);
                vl += __shfl_xor(vl, 4); vl += __shfl_xor(vl, 8);
                vr += __shfl_xor(vr, 1); vr += __shfl_xor(vr, 2);
                vr += __shfl_xor(vr, 4); vr += __shfl_xor(vr, 8);
                if (l15 == 0) {
                    sAL[wave][rt * 16 + q * 4 + r] = vl;
                    sAR[wave][rt * 16 + q * 4 + r] = vr;
                }
            }
        __syncthreads();
        if (tid < 64) {
            const int grow = mbase + tid;
            if (grow < M) {
                al[2 * grow]     = sAL[0][tid] + sAL[1][tid];   // head 0 = waves 0,1
                al[2 * grow + 1] = sAL[2][tid] + sAL[3][tid];   // head 1 = waves 2,3
                ar[2 * grow]     = sAR[0][tid] + sAR[1][tid];
                ar[2 * grow + 1] = sAR[2][tid] + sAR[3][tid];
            }
        }
    }
}

// ---------------------------------------------------------------------------
// CSR build
// ---------------------------------------------------------------------------
__device__ __forceinline__ int edge_src(const int* ei, int E, int e, int is64) {
    return is64 ? ei[2 * (size_t)e] : ei[e];
}
__device__ __forceinline__ int edge_dst(const int* ei, int E, int e, int is64) {
    return is64 ? ei[2 * (size_t)E + 2 * (size_t)e] : ei[(size_t)E + e];
}

__global__ void count_kernel(const int* __restrict__ ei, int E,
                             const int* __restrict__ flags, int* __restrict__ counts) {
    int e = blockIdx.x * blockDim.x + threadIdx.x;
    if (e < E) atomicAdd(&counts[edge_dst(ei, E, e, flags[1])], 1);
}

__global__ __launch_bounds__(1024) void scan1_kernel(const int* __restrict__ counts,
                                                     int* __restrict__ incl,
                                                     int* __restrict__ bsum, int N) {
    __shared__ int tmp[1024];
    const int t = threadIdx.x;
    const int i = blockIdx.x * 1024 + t;
    int v = (i < N) ? counts[i] : 0;
    tmp[t] = v;
    __syncthreads();
    for (int off = 1; off < 1024; off <<= 1) {
        int x = (t >= off) ? tmp[t - off] : 0;
        __syncthreads();
        tmp[t] += x;
        __syncthreads();
    }
    if (i < N) incl[i] = tmp[t];
    if (t == 1023) bsum[blockIdx.x] = tmp[1023];
}

__global__ void scan2_kernel(const int* __restrict__ bsum, int* __restrict__ boffs,
                             int nb, int* __restrict__ row_ptr, int N) {
    if (threadIdx.x == 0) {
        int run = 0;
        for (int b = 0; b < nb; b++) { boffs[b] = run; run += bsum[b]; }
        row_ptr[N] = run;
    }
}

__global__ void scan3_kernel(const int* __restrict__ incl, const int* __restrict__ counts,
                             const int* __restrict__ boffs, int* __restrict__ row_ptr,
                             int* __restrict__ fill, int N) {
    int i = blockIdx.x * blockDim.x + threadIdx.x;
    if (i < N) {
        int v = boffs[i >> 10] + incl[i] - counts[i];
        row_ptr[i] = v;
        fill[i] = v;
    }
}

__global__ void scatter_kernel(const int* __restrict__ ei, int E,
                               const int* __restrict__ flags,
                               int* __restrict__ fill, int* __restrict__ esrc) {
    int e = blockIdx.x * blockDim.x + threadIdx.x;
    if (e < E) {
        int is64 = flags[1];
        int s = edge_src(ei, E, e, is64);
        int d = edge_dst(ei, E, e, is64);
        int pos = atomicAdd(&fill[d], 1);
        esrc[pos] = s;
    }
}

// ---------------------------------------------------------------------------
// Per-node softmax weights (thread per node; avg degree 16).
// ---------------------------------------------------------------------------
__global__ void attw_kernel(const float* __restrict__ al, const float* __restrict__ ar,
                            const int* __restrict__ row_ptr, const int* __restrict__ esrc,
                            float* __restrict__ cw, int N) {
    int i = blockIdx.x * blockDim.x + threadIdx.x;
    if (i >= N) return;
    const int s0 = row_ptr[i], e0 = row_ptr[i + 1];
    if (s0 == e0) return;
    const float ar0 = ar[2 * i], ar1 = ar[2 * i + 1];
    float m0 = -INFINITY, m1 = -INFINITY;
    for (int j = s0; j < e0; j++) {
        int s = esrc[j];
        float2 av = *(const float2*)(al + 2 * s);
        float x0 = av.x + ar0; x0 = x0 > 0.f ? x0 : NEG_SLOPE * x0;
        float x1 = av.y + ar1; x1 = x1 > 0.f ? x1 : NEG_SLOPE * x1;
        cw[2 * j] = x0; cw[2 * j + 1] = x1;
        m0 = fmaxf(m0, x0); m1 = fmaxf(m1, x1);
    }
    float d0 = 0.f, d1 = 0.f;
    for (int j = s0; j < e0; j++) {
        d0 += __expf(cw[2 * j] - m0);
        d1 += __expf(cw[2 * j + 1] - m1);
    }
    const float i0 = 1.f / (d0 + SOFTMAX_EPS);
    const float i1 = 1.f / (d1 + SOFTMAX_EPS);
    for (int j = s0; j < e0; j++) {
        cw[2 * j] = __expf(cw[2 * j] - m0) * i0;
        cw[2 * j + 1] = __expf(cw[2 * j + 1] - m1) * i1;
    }
}

// ---------------------------------------------------------------------------
// Feature aggregation: block per dst node, wave-per-edge, float4/lane.
// ---------------------------------------------------------------------------
__global__ __launch_bounds__(256) void aggf_kernel(const float* __restrict__ xl,
                                                   const float* __restrict__ cw,
                                                   const int* __restrict__ row_ptr,
                                                   const int* __restrict__ esrc,
                                                   __bf16* __restrict__ hhi,
                                                   __bf16* __restrict__ hlo) {
    const int i = blockIdx.x;
    const int t = threadIdx.x;
    const int lane = t & 63;
    const int wave = t >> 6;
    const int s0 = row_ptr[i], e0 = row_ptr[i + 1];
    const int hsel = lane >> 5;

    float4 acc = {0.f, 0.f, 0.f, 0.f};
    for (int j = s0 + wave; j < e0; j += 4) {
        int s = esrc[j];
        float w = cw[2 * j + hsel];
        float4 xv = *(const float4*)(xl + (size_t)s * HC + lane * 4);
        acc.x += w * xv.x; acc.y += w * xv.y; acc.z += w * xv.z; acc.w += w * xv.w;
    }

    __shared__ float red[3][256];
    if (wave > 0) *(float4*)&red[wave - 1][lane * 4] = acc;
    __syncthreads();
    if (wave == 0) {
        const int c4 = lane * 4;
        acc.x += red[0][c4] + red[1][c4] + red[2][c4];
        acc.y += red[0][c4 + 1] + red[1][c4 + 1] + red[2][c4 + 1];
        acc.z += red[0][c4 + 2] + red[1][c4 + 2] + red[2][c4 + 2];
        acc.w += red[0][c4 + 3] + red[1][c4 + 3] + red[2][c4 + 3];
        const size_t base = (size_t)i * HC + c4;
        float vv[4] = {acc.x, acc.y, acc.z, acc.w};
#pragma unroll
        for (int c = 0; c < 4; c++) {
            float v = fmaxf(vv[c], 0.f);
            __bf16 h = (__bf16)v;
            hhi[base + c] = h;
            hlo[base + c] = (__bf16)(v - (float)h);
        }
    }
}

// ---------------------------------------------------------------------------
extern "C" void kernel_launch(void* const* d_in, const int* in_sizes, int n_in,
                              void* d_out, int out_size, void* d_ws, size_t ws_size,
                              hipStream_t stream) {
    const int D = 128;
    const int N = in_sizes[0] / D;   // 50000
    const int E = in_sizes[1] / 2;   // 800000
    const int* ei = (const int*)d_in[1];

    char* w = (char*)d_ws;
    auto alloc = [&](size_t bytes) {
        void* p = w;
        w += (bytes + 255) & ~(size_t)255;
        return p;
    };
    int*    flags  = (int*)   alloc(256);
    __bf16* x_hi   = (__bf16*)alloc((size_t)N * D * 2);
    __bf16* x_lo   = (__bf16*)alloc((size_t)N * D * 2);
    __bf16* W1h    = (__bf16*)alloc((size_t)in_sizes[2] * 2);
    __bf16* W1l    = (__bf16*)alloc((size_t)in_sizes[2] * 2);
    __bf16* W2h    = (__bf16*)alloc((size_t)in_sizes[5] * 2);
    __bf16* W2l    = (__bf16*)alloc((size_t)in_sizes[5] * 2);
    __bf16* Wp1h   = (__bf16*)alloc((size_t)in_sizes[8] * 2);
    __bf16* Wp1l   = (__bf16*)alloc((size_t)in_sizes[8] * 2);
    __bf16* Wp2h   = (__bf16*)alloc((size_t)in_sizes[10] * 2);
    __bf16* Wp2l   = (__bf16*)alloc((size_t)in_sizes[10] * 2);
    float*  atl1   = (float*) alloc((size_t)in_sizes[3] * 4);
    float*  atr1   = (float*) alloc((size_t)in_sizes[4] * 4);
    float*  atl2   = (float*) alloc((size_t)in_sizes[6] * 4);
    float*  atr2   = (float*) alloc((size_t)in_sizes[7] * 4);
    float*  bfp1   = (float*) alloc((size_t)in_sizes[9] * 4);
    float*  bfp2   = (float*) alloc((size_t)in_sizes[11] * 4);
    float*  xl     = (float*) alloc((size_t)N * HC * 4);
    __bf16* h_hi   = (__bf16*)alloc((size_t)N * HC * 2);
    __bf16* h_lo   = (__bf16*)alloc((size_t)N * HC * 2);
    float*  al     = (float*) alloc((size_t)N * 2 * 4);
    float*  ar     = (float*) alloc((size_t)N * 2 * 4);
    int*    counts = (int*)   alloc((size_t)N * 4);
    int*    incl   = (int*)   alloc((size_t)N * 4);
    int*    row_ptr= (int*)   alloc((size_t)(N + 1) * 4);
    int*    fill   = (int*)   alloc((size_t)N * 4);
    int*    bsum   = (int*)   alloc(1024);
    int*    boffs  = (int*)   alloc(1024);
    int*    esrc   = (int*)   alloc((size_t)E * 4);
    float*  cw     = (float*) alloc((size_t)E * 2 * 4);

    const int EB = (E + 255) / 256;
    const int GM = (N + 63) / 64;
    const int NB1024 = (N + 1023) / 1024;

    // 0. dtype sniff + canonicalize
    detect_kernel<<<1, 256, 0, stream>>>((const uint32_t*)d_in[0], (const uint32_t*)d_in[1], flags);
    conv_small_kernel<<<1, 256, 0, stream>>>(d_in[3], atl1, in_sizes[3],
                                             d_in[4], atr1, in_sizes[4],
                                             d_in[6], atl2, in_sizes[6],
                                             d_in[7], atr2, in_sizes[7],
                                             d_in[9], bfp1, in_sizes[9],
                                             d_in[11], bfp2, in_sizes[11], flags);
    split_kernel<<<(in_sizes[0] + 255) / 256, 256, 0, stream>>>(d_in[0], x_hi, x_lo, in_sizes[0], flags);
    {
        int nt = in_sizes[2] + in_sizes[5] + in_sizes[8] + in_sizes[10];
        split4_kernel<<<(nt + 255) / 256, 256, 0, stream>>>(
            d_in[2], W1h, W1l, in_sizes[2],
            d_in[5], W2h, W2l, in_sizes[5],
            d_in[8], Wp1h, Wp1l, in_sizes[8],
            d_in[10], Wp2h, Wp2l, in_sizes[10], flags);
    }

    // 1. CSR build
    hipMemsetAsync(counts, 0, (size_t)N * 4, stream);
    count_kernel<<<EB, 256, 0, stream>>>(ei, E, flags, counts);
    scan1_kernel<<<NB1024, 1024, 0, stream>>>(counts, incl, bsum, N);
    scan2_kernel<<<1, 64, 0, stream>>>(bsum, boffs, NB1024, row_ptr, N);
    scan3_kernel<<<(N + 255) / 256, 256, 0, stream>>>(incl, counts, boffs, row_ptr, fill, N);
    scatter_kernel<<<EB, 256, 0, stream>>>(ei, E, flags, fill, esrc);

    // 2. GAT layer 1: xl = x@W1^T (alpha fused), K=128
    gemm_bt<128, 16, false, true, false><<<GM, 256, 0, stream>>>(
        x_hi, x_lo, W1h, W1l, nullptr, xl, nullptr, nullptr, atl1, atr1, al, ar, N);
    attw_kernel<<<(N + 255) / 256, 256, 0, stream>>>(al, ar, row_ptr, esrc, cw, N);
    aggf_kernel<<<N, 256, 0, stream>>>(xl, cw, row_ptr, esrc, h_hi, h_lo);

    // 3. GAT layer 2: xl = h1@W2^T (alpha fused), K=256
    gemm_bt<256, 16, false, true, false><<<GM, 256, 0, stream>>>(
        h_hi, h_lo, W2h, W2l, nullptr, xl, nullptr, nullptr, atl2, atr2, al, ar, N);
    attw_kernel<<<(N + 255) / 256, 256, 0, stream>>>(al, ar, row_ptr, esrc, cw, N);
    aggf_kernel<<<N, 256, 0, stream>>>(xl, cw, row_ptr, esrc, h_hi, h_lo);

    // 4. projections: p = h2@Wp1^T + bp1 (K=256, O=128, hi/lo out into x bufs)
    gemm_bt<256, 8, true, false, true><<<GM, 256, 0, stream>>>(
        h_hi, h_lo, Wp1h, Wp1l, bfp1, nullptr, x_hi, x_lo, nullptr, nullptr, nullptr, nullptr, N);
    // out = p@Wp2^T + bp2 (K=128, O=128) -> f32 d_out
    gemm_bt<128, 8, true, false, false><<<GM, 256, 0, stream>>>(
        x_hi, x_lo, Wp2h, Wp2l, bfp2, (float*)d_out, nullptr, nullptr, nullptr, nullptr, nullptr, nullptr, N);
}

// Round 6
// 653.975 us; speedup vs baseline: 1.5764x; 1.0619x over previous
//
#include <hip/hip_runtime.h>
#include <hip/hip_bf16.h>
#include <stdint.h>

// TermEncoder GAT: N=50000, E=800000, D=128, H=2, C=128, HC=256
// R6: aggf is bytes-bound (383 MB fetch, 47% HBM, VALU 21%). Store xl as fp16
// (only consumer is the gather) -> halve gather+write traffic. attw 128-thr
// blocks. GEMM structure unchanged from r5 (latency fix verified).
#define HC 256
#define NEG_SLOPE 0.2f
#define SOFTMAX_EPS 1e-16f

typedef __bf16 bf16x8 __attribute__((ext_vector_type(8)));
typedef float floatx4 __attribute__((ext_vector_type(4)));
typedef _Float16 half4v __attribute__((ext_vector_type(4)));

// ---------------------------------------------------------------------------
// dtype sniffing: flags[0]=float-is-bf16, flags[1]=edge-index-is-int64.
// ---------------------------------------------------------------------------
__global__ void detect_kernel(const uint32_t* __restrict__ xw,
                              const uint32_t* __restrict__ ew,
                              int* __restrict__ flags) {
    __shared__ int cnt_bf16, cnt_odd_nz;
    const int t = threadIdx.x;
    if (t == 0) { cnt_bf16 = 0; cnt_odd_nz = 0; }
    __syncthreads();
    uint32_t w = xw[t];
    uint32_t ef = ((w & 0xFFFFu) >> 7) & 0xFFu;
    if (ef >= 90u && ef <= 135u) atomicAdd(&cnt_bf16, 1);
    if (t < 64 && ew[2 * t + 1] != 0u) atomicAdd(&cnt_odd_nz, 1);
    __syncthreads();
    if (t == 0) {
        flags[0] = (cnt_bf16 > 192) ? 1 : 0;
        flags[1] = (cnt_odd_nz == 0) ? 1 : 0;
    }
}

__device__ __forceinline__ float in_load(const void* p, int i, int is_bf16) {
    return is_bf16 ? (float)((const __bf16*)p)[i] : ((const float*)p)[i];
}

__global__ void conv_small_kernel(const void* a0, float* o0, int n0,
                                  const void* a1, float* o1, int n1,
                                  const void* a2, float* o2, int n2,
                                  const void* a3, float* o3, int n3,
                                  const void* a4, float* o4, int n4,
                                  const void* a5, float* o5, int n5,
                                  const int* __restrict__ flags) {
    const int t = threadIdx.x;
    const int fb = flags[0];
    if (t < n0) o0[t] = in_load(a0, t, fb);
    if (t < n1) o1[t] = in_load(a1, t, fb);
    if (t < n2) o2[t] = in_load(a2, t, fb);
    if (t < n3) o3[t] = in_load(a3, t, fb);
    if (t < n4) o4[t] = in_load(a4, t, fb);
    if (t < n5) o5[t] = in_load(a5, t, fb);
}

__global__ void split_kernel(const void* __restrict__ in, __bf16* __restrict__ hi,
                             __bf16* __restrict__ lo, int n, const int* __restrict__ flags) {
    int i = blockIdx.x * blockDim.x + threadIdx.x;
    if (i >= n) return;
    float v = in_load(in, i, flags[0]);
    __bf16 h = (__bf16)v;
    hi[i] = h;
    lo[i] = (__bf16)(v - (float)h);
}

__global__ void split4_kernel(const void* i0, __bf16* h0, __bf16* l0, int n0,
                              const void* i1, __bf16* h1, __bf16* l1, int n1,
                              const void* i2, __bf16* h2, __bf16* l2, int n2,
                              const void* i3, __bf16* h3, __bf16* l3, int n3,
                              const int* __restrict__ flags) {
    int idx = blockIdx.x * blockDim.x + threadIdx.x;
    const void* in;
    __bf16 *ph, *pl;
    int off = idx;
    if (off < n0)      { in = i0; ph = h0; pl = l0; }
    else if ((off -= n0) < n1) { in = i1; ph = h1; pl = l1; }
    else if ((off -= n1) < n2) { in = i2; ph = h2; pl = l2; }
    else if ((off -= n2) < n3) { in = i3; ph = h3; pl = l3; }
    else return;
    float v = in_load(in, off, flags[0]);
    __bf16 h = (__bf16)v;
    ph[off] = h;
    pl[off] = (__bf16)(v - (float)h);
}

// ---------------------------------------------------------------------------
// GEMM: C[M,O] = A[M,KTEMP]@B[O,KTEMP]^T (+bias), pre-split bf16 hi/lo.
// Wave w owns O/4 cols; batched loads, K fully unrolled (r5 structure).
// OMODE: 0=f32, 1=bf16 hi/lo split, 2=fp16.
// ---------------------------------------------------------------------------
template <int KTEMP, int OTILES, bool BIAS, bool ALPHA, int OMODE>
__global__ __launch_bounds__(256) void gemm_bt(
    const __bf16* __restrict__ Ahi, const __bf16* __restrict__ Alo,
    const __bf16* __restrict__ Bhi, const __bf16* __restrict__ Blo,
    const float* __restrict__ bias,
    float* __restrict__ C, __bf16* __restrict__ Chi, __bf16* __restrict__ Clo,
    _Float16* __restrict__ Cf16,
    const float* __restrict__ attl, const float* __restrict__ attr,
    float* __restrict__ al, float* __restrict__ ar,
    int M) {
    static_assert(!ALPHA || OTILES == 16, "alpha fusion assumes O=256");
    constexpr int TW = OTILES / 4;
    constexpr int O = OTILES * 16;
    const int tid = threadIdx.x;
    const int lane = tid & 63;
    const int wave = tid >> 6;
    const int mbase = blockIdx.x * 64;
    const int l15 = lane & 15;
    const int q = lane >> 4;
    const int kq = q * 8;
    const int wc = wave * TW * 16;

    int arow[4];
#pragma unroll
    for (int rt = 0; rt < 4; rt++) arow[rt] = min(mbase + rt * 16 + l15, M - 1);

    floatx4 acc[4][TW];
#pragma unroll
    for (int rt = 0; rt < 4; rt++)
#pragma unroll
        for (int tt = 0; tt < TW; tt++) acc[rt][tt] = (floatx4){0.f, 0.f, 0.f, 0.f};

    constexpr int KSTEPS = KTEMP / 32;
#pragma unroll
    for (int ks = 0; ks < KSTEPS; ks++) {
        const int k0 = ks * 32;
        bf16x8 ah[4], alo_[4], bh[TW], bl_[TW];
#pragma unroll
        for (int rt = 0; rt < 4; rt++) {
            const size_t off = (size_t)arow[rt] * KTEMP + k0 + kq;
            ah[rt] = *(const bf16x8*)(Ahi + off);
            alo_[rt] = *(const bf16x8*)(Alo + off);
        }
#pragma unroll
        for (int tt = 0; tt < TW; tt++) {
            const size_t off = (size_t)(wc + tt * 16 + l15) * KTEMP + k0 + kq;
            bh[tt] = *(const bf16x8*)(Bhi + off);
            bl_[tt] = *(const bf16x8*)(Blo + off);
        }
#pragma unroll
        for (int rt = 0; rt < 4; rt++)
#pragma unroll
            for (int tt = 0; tt < TW; tt++) {
                acc[rt][tt] = __builtin_amdgcn_mfma_f32_16x16x32_bf16(ah[rt], bh[tt], acc[rt][tt], 0, 0, 0);
                acc[rt][tt] = __builtin_amdgcn_mfma_f32_16x16x32_bf16(alo_[rt], bh[tt], acc[rt][tt], 0, 0, 0);
                acc[rt][tt] = __builtin_amdgcn_mfma_f32_16x16x32_bf16(ah[rt], bl_[tt], acc[rt][tt], 0, 0, 0);
            }
    }

    // C/D layout: col = lane&15, row(in tile) = q*4 + reg  [m89/m91]
    float aLp[4][4], aRp[4][4];
    if constexpr (ALPHA) {
#pragma unroll
        for (int rt = 0; rt < 4; rt++)
#pragma unroll
            for (int r = 0; r < 4; r++) { aLp[rt][r] = 0.f; aRp[rt][r] = 0.f; }
    }

#pragma unroll
    for (int rt = 0; rt < 4; rt++) {
        const int rb = mbase + rt * 16 + q * 4;
#pragma unroll
        for (int tt = 0; tt < TW; tt++) {
            const int gcol = wc + tt * 16 + l15;
            float atlv = 0.f, atrv = 0.f;
            if constexpr (ALPHA) { atlv = attl[gcol]; atrv = attr[gcol]; }
#pragma unroll
            for (int r = 0; r < 4; r++) {
                float v = acc[rt][tt][r];
                if constexpr (BIAS) v += bias[gcol];
                if constexpr (ALPHA) { aLp[rt][r] += v * atlv; aRp[rt][r] += v * atrv; }
                const int grow = rb + r;
                if (grow < M) {
                    if constexpr (OMODE == 1) {
                        __bf16 h = (__bf16)v;
                        Chi[(size_t)grow * O + gcol] = h;
                        Clo[(size_t)grow * O + gcol] = (__bf16)(v - (float)h);
                    } else if constexpr (OMODE == 2) {
                        Cf16[(size_t)grow * O + gcol] = (_Float16)v;
                    } else {
                        C[(size_t)grow * O + gcol] = v;
                    }
                }
            }
        }
    }

    if constexpr (ALPHA) {
        __shared__ float sAL[4][64], sAR[4][64];
#pragma unroll
        for (int rt = 0; rt < 4; rt++)
#pragma unroll
            for (int r = 0; r < 4; r++) {
                float vl = aLp[rt][r], vr = aRp[rt][r];
                vl += __shfl_xor(vl, 1); vl += __shfl_xor(vl, 2);
                vl += __shfl_xor(vl, 4); vl += __shfl_xor(vl, 8);
                vr += __shfl_xor(vr, 1); vr += __shfl_xor(vr, 2);
                vr += __shfl_xor(vr, 4); vr += __shfl_xor(vr, 8);
                if (l15 == 0) {
                    sAL[wave][rt * 16 + q * 4 + r] = vl;
                    sAR[wave][rt * 16 + q * 4 + r] = vr;
                }
            }
        __syncthreads();
        if (tid < 64) {
            const int grow = mbase + tid;
            if (grow < M) {
                al[2 * grow]     = sAL[0][tid] + sAL[1][tid];
                al[2 * grow + 1] = sAL[2][tid] + sAL[3][tid];
                ar[2 * grow]     = sAR[0][tid] + sAR[1][tid];
                ar[2 * grow + 1] = sAR[2][tid] + sAR[3][tid];
            }
        }
    }
}

// ---------------------------------------------------------------------------
// CSR build
// ---------------------------------------------------------------------------
__device__ __forceinline__ int edge_src(const int* ei, int E, int e, int is64) {
    return is64 ? ei[2 * (size_t)e] : ei[e];
}
__device__ __forceinline__ int edge_dst(const int* ei, int E, int e, int is64) {
    return is64 ? ei[2 * (size_t)E + 2 * (size_t)e] : ei[(size_t)E + e];
}

__global__ void count_kernel(const int* __restrict__ ei, int E,
                             const int* __restrict__ flags, int* __restrict__ counts) {
    int e = blockIdx.x * blockDim.x + threadIdx.x;
    if (e < E) atomicAdd(&counts[edge_dst(ei, E, e, flags[1])], 1);
}

__global__ __launch_bounds__(1024) void scan1_kernel(const int* __restrict__ counts,
                                                     int* __restrict__ incl,
                                                     int* __restrict__ bsum, int N) {
    __shared__ int tmp[1024];
    const int t = threadIdx.x;
    const int i = blockIdx.x * 1024 + t;
    int v = (i < N) ? counts[i] : 0;
    tmp[t] = v;
    __syncthreads();
    for (int off = 1; off < 1024; off <<= 1) {
        int x = (t >= off) ? tmp[t - off] : 0;
        __syncthreads();
        tmp[t] += x;
        __syncthreads();
    }
    if (i < N) incl[i] = tmp[t];
    if (t == 1023) bsum[blockIdx.x] = tmp[1023];
}

__global__ void scan2_kernel(const int* __restrict__ bsum, int* __restrict__ boffs,
                             int nb, int* __restrict__ row_ptr, int N) {
    if (threadIdx.x == 0) {
        int run = 0;
        for (int b = 0; b < nb; b++) { boffs[b] = run; run += bsum[b]; }
        row_ptr[N] = run;
    }
}

__global__ void scan3_kernel(const int* __restrict__ incl, const int* __restrict__ counts,
                             const int* __restrict__ boffs, int* __restrict__ row_ptr,
                             int* __restrict__ fill, int N) {
    int i = blockIdx.x * blockDim.x + threadIdx.x;
    if (i < N) {
        int v = boffs[i >> 10] + incl[i] - counts[i];
        row_ptr[i] = v;
        fill[i] = v;
    }
}

__global__ void scatter_kernel(const int* __restrict__ ei, int E,
                               const int* __restrict__ flags,
                               int* __restrict__ fill, int* __restrict__ esrc) {
    int e = blockIdx.x * blockDim.x + threadIdx.x;
    if (e < E) {
        int is64 = flags[1];
        int s = edge_src(ei, E, e, is64);
        int d = edge_dst(ei, E, e, is64);
        int pos = atomicAdd(&fill[d], 1);
        esrc[pos] = s;
    }
}

// ---------------------------------------------------------------------------
// Per-node softmax weights (thread per node; avg degree 16). 128-thr blocks.
// ---------------------------------------------------------------------------
__global__ __launch_bounds__(128) void attw_kernel(const float* __restrict__ al,
                                                   const float* __restrict__ ar,
                                                   const int* __restrict__ row_ptr,
                                                   const int* __restrict__ esrc,
                                                   float* __restrict__ cw, int N) {
    int i = blockIdx.x * blockDim.x + threadIdx.x;
    if (i >= N) return;
    const int s0 = row_ptr[i], e0 = row_ptr[i + 1];
    if (s0 == e0) return;
    const float ar0 = ar[2 * i], ar1 = ar[2 * i + 1];
    float m0 = -INFINITY, m1 = -INFINITY;
    for (int j = s0; j < e0; j++) {
        int s = esrc[j];
        float2 av = *(const float2*)(al + 2 * s);
        float x0 = av.x + ar0; x0 = x0 > 0.f ? x0 : NEG_SLOPE * x0;
        float x1 = av.y + ar1; x1 = x1 > 0.f ? x1 : NEG_SLOPE * x1;
        cw[2 * j] = x0; cw[2 * j + 1] = x1;
        m0 = fmaxf(m0, x0); m1 = fmaxf(m1, x1);
    }
    float d0 = 0.f, d1 = 0.f;
    for (int j = s0; j < e0; j++) {
        d0 += __expf(cw[2 * j] - m0);
        d1 += __expf(cw[2 * j + 1] - m1);
    }
    const float i0 = 1.f / (d0 + SOFTMAX_EPS);
    const float i1 = 1.f / (d1 + SOFTMAX_EPS);
    for (int j = s0; j < e0; j++) {
        cw[2 * j] = __expf(cw[2 * j] - m0) * i0;
        cw[2 * j + 1] = __expf(cw[2 * j + 1] - m1) * i1;
    }
}

// ---------------------------------------------------------------------------
// Feature aggregation: block per dst node, wave-per-edge, fp16 half4/lane.
// ---------------------------------------------------------------------------
__global__ __launch_bounds__(256) void aggf_kernel(const _Float16* __restrict__ xl,
                                                   const float* __restrict__ cw,
                                                   const int* __restrict__ row_ptr,
                                                   const int* __restrict__ esrc,
                                                   __bf16* __restrict__ hhi,
                                                   __bf16* __restrict__ hlo) {
    const int i = blockIdx.x;
    const int t = threadIdx.x;
    const int lane = t & 63;
    const int wave = t >> 6;
    const int s0 = row_ptr[i], e0 = row_ptr[i + 1];
    const int hsel = lane >> 5;

    float4 acc = {0.f, 0.f, 0.f, 0.f};
    for (int j = s0 + wave; j < e0; j += 4) {
        int s = esrc[j];
        float w = cw[2 * j + hsel];
        half4v xv = *(const half4v*)(xl + (size_t)s * HC + lane * 4);
        acc.x += w * (float)xv[0];
        acc.y += w * (float)xv[1];
        acc.z += w * (float)xv[2];
        acc.w += w * (float)xv[3];
    }

    __shared__ float red[3][256];
    if (wave > 0) *(float4*)&red[wave - 1][lane * 4] = acc;
    __syncthreads();
    if (wave == 0) {
        const int c4 = lane * 4;
        acc.x += red[0][c4] + red[1][c4] + red[2][c4];
        acc.y += red[0][c4 + 1] + red[1][c4 + 1] + red[2][c4 + 1];
        acc.z += red[0][c4 + 2] + red[1][c4 + 2] + red[2][c4 + 2];
        acc.w += red[0][c4 + 3] + red[1][c4 + 3] + red[2][c4 + 3];
        const size_t base = (size_t)i * HC + c4;
        float vv[4] = {acc.x, acc.y, acc.z, acc.w};
#pragma unroll
        for (int c = 0; c < 4; c++) {
            float v = fmaxf(vv[c], 0.f);
            __bf16 h = (__bf16)v;
            hhi[base + c] = h;
            hlo[base + c] = (__bf16)(v - (float)h);
        }
    }
}

// ---------------------------------------------------------------------------
extern "C" void kernel_launch(void* const* d_in, const int* in_sizes, int n_in,
                              void* d_out, int out_size, void* d_ws, size_t ws_size,
                              hipStream_t stream) {
    const int D = 128;
    const int N = in_sizes[0] / D;   // 50000
    const int E = in_sizes[1] / 2;   // 800000
    const int* ei = (const int*)d_in[1];

    char* w = (char*)d_ws;
    auto alloc = [&](size_t bytes) {
        void* p = w;
        w += (bytes + 255) & ~(size_t)255;
        return p;
    };
    int*      flags  = (int*)     alloc(256);
    __bf16*   x_hi   = (__bf16*)  alloc((size_t)N * D * 2);
    __bf16*   x_lo   = (__bf16*)  alloc((size_t)N * D * 2);
    __bf16*   W1h    = (__bf16*)  alloc((size_t)in_sizes[2] * 2);
    __bf16*   W1l    = (__bf16*)  alloc((size_t)in_sizes[2] * 2);
    __bf16*   W2h    = (__bf16*)  alloc((size_t)in_sizes[5] * 2);
    __bf16*   W2l    = (__bf16*)  alloc((size_t)in_sizes[5] * 2);
    __bf16*   Wp1h   = (__bf16*)  alloc((size_t)in_sizes[8] * 2);
    __bf16*   Wp1l   = (__bf16*)  alloc((size_t)in_sizes[8] * 2);
    __bf16*   Wp2h   = (__bf16*)  alloc((size_t)in_sizes[10] * 2);
    __bf16*   Wp2l   = (__bf16*)  alloc((size_t)in_sizes[10] * 2);
    float*    atl1   = (float*)   alloc((size_t)in_sizes[3] * 4);
    float*    atr1   = (float*)   alloc((size_t)in_sizes[4] * 4);
    float*    atl2   = (float*)   alloc((size_t)in_sizes[6] * 4);
    float*    atr2   = (float*)   alloc((size_t)in_sizes[7] * 4);
    float*    bfp1   = (float*)   alloc((size_t)in_sizes[9] * 4);
    float*    bfp2   = (float*)   alloc((size_t)in_sizes[11] * 4);
    _Float16* xl16   = (_Float16*)alloc((size_t)N * HC * 2);   // 25.6 MB
    __bf16*   h_hi   = (__bf16*)  alloc((size_t)N * HC * 2);
    __bf16*   h_lo   = (__bf16*)  alloc((size_t)N * HC * 2);
    float*    al     = (float*)   alloc((size_t)N * 2 * 4);
    float*    ar     = (float*)   alloc((size_t)N * 2 * 4);
    int*      counts = (int*)     alloc((size_t)N * 4);
    int*      incl   = (int*)     alloc((size_t)N * 4);
    int*      row_ptr= (int*)     alloc((size_t)(N + 1) * 4);
    int*      fill   = (int*)     alloc((size_t)N * 4);
    int*      bsum   = (int*)     alloc(1024);
    int*      boffs  = (int*)     alloc(1024);
    int*      esrc   = (int*)     alloc((size_t)E * 4);
    float*    cw     = (float*)   alloc((size_t)E * 2 * 4);

    const int EB = (E + 255) / 256;
    const int GM = (N + 63) / 64;
    const int NB1024 = (N + 1023) / 1024;

    // 0. dtype sniff + canonicalize
    detect_kernel<<<1, 256, 0, stream>>>((const uint32_t*)d_in[0], (const uint32_t*)d_in[1], flags);
    conv_small_kernel<<<1, 256, 0, stream>>>(d_in[3], atl1, in_sizes[3],
                                             d_in[4], atr1, in_sizes[4],
                                             d_in[6], atl2, in_sizes[6],
                                             d_in[7], atr2, in_sizes[7],
                                             d_in[9], bfp1, in_sizes[9],
                                             d_in[11], bfp2, in_sizes[11], flags);
    split_kernel<<<(in_sizes[0] + 255) / 256, 256, 0, stream>>>(d_in[0], x_hi, x_lo, in_sizes[0], flags);
    {
        int nt = in_sizes[2] + in_sizes[5] + in_sizes[8] + in_sizes[10];
        split4_kernel<<<(nt + 255) / 256, 256, 0, stream>>>(
            d_in[2], W1h, W1l, in_sizes[2],
            d_in[5], W2h, W2l, in_sizes[5],
            d_in[8], Wp1h, Wp1l, in_sizes[8],
            d_in[10], Wp2h, Wp2l, in_sizes[10], flags);
    }

    // 1. CSR build
    hipMemsetAsync(counts, 0, (size_t)N * 4, stream);
    count_kernel<<<EB, 256, 0, stream>>>(ei, E, flags, counts);
    scan1_kernel<<<NB1024, 1024, 0, stream>>>(counts, incl, bsum, N);
    scan2_kernel<<<1, 64, 0, stream>>>(bsum, boffs, NB1024, row_ptr, N);
    scan3_kernel<<<(N + 255) / 256, 256, 0, stream>>>(incl, counts, boffs, row_ptr, fill, N);
    scatter_kernel<<<EB, 256, 0, stream>>>(ei, E, flags, fill, esrc);

    // 2. GAT layer 1: xl16 = x@W1^T (fp16 out, alpha fused), K=128
    gemm_bt<128, 16, false, true, 2><<<GM, 256, 0, stream>>>(
        x_hi, x_lo, W1h, W1l, nullptr, nullptr, nullptr, nullptr, xl16, atl1, atr1, al, ar, N);
    attw_kernel<<<(N + 127) / 128, 128, 0, stream>>>(al, ar, row_ptr, esrc, cw, N);
    aggf_kernel<<<N, 256, 0, stream>>>(xl16, cw, row_ptr, esrc, h_hi, h_lo);

    // 3. GAT layer 2: xl16 = h1@W2^T (fp16 out, alpha fused), K=256
    gemm_bt<256, 16, false, true, 2><<<GM, 256, 0, stream>>>(
        h_hi, h_lo, W2h, W2l, nullptr, nullptr, nullptr, nullptr, xl16, atl2, atr2, al, ar, N);
    attw_kernel<<<(N + 127) / 128, 128, 0, stream>>>(al, ar, row_ptr, esrc, cw, N);
    aggf_kernel<<<N, 256, 0, stream>>>(xl16, cw, row_ptr, esrc, h_hi, h_lo);

    // 4. projections: p = h2@Wp1^T + bp1 (K=256, O=128, bf16 hi/lo out)
    gemm_bt<256, 8, true, false, 1><<<GM, 256, 0, stream>>>(
        h_hi, h_lo, Wp1h, Wp1l, bfp1, nullptr, x_hi, x_lo, nullptr, nullptr, nullptr, nullptr, nullptr, N);
    // out = p@Wp2^T + bp2 (K=128, O=128) -> f32 d_out
    gemm_bt<128, 8, true, false, 0><<<GM, 256, 0, stream>>>(
        x_hi, x_lo, Wp2h, Wp2l, bfp2, (float*)d_out, nullptr, nullptr, nullptr, nullptr, nullptr, nullptr, nullptr, N);
}

// Round 7
// 530.021 us; speedup vs baseline: 1.9450x; 1.2339x over previous
//
#include <hip/hip_runtime.h>
#include <hip/hip_bf16.h>
#include <stdint.h>

// TermEncoder GAT: N=50000, E=800000, D=128, H=2, C=128, HC=256
// R7: fused flash-style segment-softmax+aggregate, wave-per-node (no barriers,
// no LDS), online softmax, half8 gathers (2 edges/iter/wave). attw + cw gone.
// GEMM/CSR unchanged from r6.
#define HC 256
#define NEG_SLOPE 0.2f
#define SOFTMAX_EPS 1e-16f

typedef __bf16 bf16x8 __attribute__((ext_vector_type(8)));
typedef float floatx4 __attribute__((ext_vector_type(4)));
typedef _Float16 half8v __attribute__((ext_vector_type(8)));

// ---------------------------------------------------------------------------
// dtype sniffing: flags[0]=float-is-bf16, flags[1]=edge-index-is-int64.
// ---------------------------------------------------------------------------
__global__ void detect_kernel(const uint32_t* __restrict__ xw,
                              const uint32_t* __restrict__ ew,
                              int* __restrict__ flags) {
    __shared__ int cnt_bf16, cnt_odd_nz;
    const int t = threadIdx.x;
    if (t == 0) { cnt_bf16 = 0; cnt_odd_nz = 0; }
    __syncthreads();
    uint32_t w = xw[t];
    uint32_t ef = ((w & 0xFFFFu) >> 7) & 0xFFu;
    if (ef >= 90u && ef <= 135u) atomicAdd(&cnt_bf16, 1);
    if (t < 64 && ew[2 * t + 1] != 0u) atomicAdd(&cnt_odd_nz, 1);
    __syncthreads();
    if (t == 0) {
        flags[0] = (cnt_bf16 > 192) ? 1 : 0;
        flags[1] = (cnt_odd_nz == 0) ? 1 : 0;
    }
}

__device__ __forceinline__ float in_load(const void* p, int i, int is_bf16) {
    return is_bf16 ? (float)((const __bf16*)p)[i] : ((const float*)p)[i];
}

__global__ void conv_small_kernel(const void* a0, float* o0, int n0,
                                  const void* a1, float* o1, int n1,
                                  const void* a2, float* o2, int n2,
                                  const void* a3, float* o3, int n3,
                                  const void* a4, float* o4, int n4,
                                  const void* a5, float* o5, int n5,
                                  const int* __restrict__ flags) {
    const int t = threadIdx.x;
    const int fb = flags[0];
    if (t < n0) o0[t] = in_load(a0, t, fb);
    if (t < n1) o1[t] = in_load(a1, t, fb);
    if (t < n2) o2[t] = in_load(a2, t, fb);
    if (t < n3) o3[t] = in_load(a3, t, fb);
    if (t < n4) o4[t] = in_load(a4, t, fb);
    if (t < n5) o5[t] = in_load(a5, t, fb);
}

__global__ void split_kernel(const void* __restrict__ in, __bf16* __restrict__ hi,
                             __bf16* __restrict__ lo, int n, const int* __restrict__ flags) {
    int i = blockIdx.x * blockDim.x + threadIdx.x;
    if (i >= n) return;
    float v = in_load(in, i, flags[0]);
    __bf16 h = (__bf16)v;
    hi[i] = h;
    lo[i] = (__bf16)(v - (float)h);
}

__global__ void split4_kernel(const void* i0, __bf16* h0, __bf16* l0, int n0,
                              const void* i1, __bf16* h1, __bf16* l1, int n1,
                              const void* i2, __bf16* h2, __bf16* l2, int n2,
                              const void* i3, __bf16* h3, __bf16* l3, int n3,
                              const int* __restrict__ flags) {
    int idx = blockIdx.x * blockDim.x + threadIdx.x;
    const void* in;
    __bf16 *ph, *pl;
    int off = idx;
    if (off < n0)      { in = i0; ph = h0; pl = l0; }
    else if ((off -= n0) < n1) { in = i1; ph = h1; pl = l1; }
    else if ((off -= n1) < n2) { in = i2; ph = h2; pl = l2; }
    else if ((off -= n2) < n3) { in = i3; ph = h3; pl = l3; }
    else return;
    float v = in_load(in, off, flags[0]);
    __bf16 h = (__bf16)v;
    ph[off] = h;
    pl[off] = (__bf16)(v - (float)h);
}

// ---------------------------------------------------------------------------
// GEMM: C[M,O] = A[M,KTEMP]@B[O,KTEMP]^T (+bias), pre-split bf16 hi/lo.
// Wave w owns O/4 cols; batched loads, K fully unrolled (r5 structure).
// OMODE: 0=f32, 1=bf16 hi/lo split, 2=fp16.
// ---------------------------------------------------------------------------
template <int KTEMP, int OTILES, bool BIAS, bool ALPHA, int OMODE>
__global__ __launch_bounds__(256) void gemm_bt(
    const __bf16* __restrict__ Ahi, const __bf16* __restrict__ Alo,
    const __bf16* __restrict__ Bhi, const __bf16* __restrict__ Blo,
    const float* __restrict__ bias,
    float* __restrict__ C, __bf16* __restrict__ Chi, __bf16* __restrict__ Clo,
    _Float16* __restrict__ Cf16,
    const float* __restrict__ attl, const float* __restrict__ attr,
    float* __restrict__ al, float* __restrict__ ar,
    int M) {
    static_assert(!ALPHA || OTILES == 16, "alpha fusion assumes O=256");
    constexpr int TW = OTILES / 4;
    constexpr int O = OTILES * 16;
    const int tid = threadIdx.x;
    const int lane = tid & 63;
    const int wave = tid >> 6;
    const int mbase = blockIdx.x * 64;
    const int l15 = lane & 15;
    const int q = lane >> 4;
    const int kq = q * 8;
    const int wc = wave * TW * 16;

    int arow[4];
#pragma unroll
    for (int rt = 0; rt < 4; rt++) arow[rt] = min(mbase + rt * 16 + l15, M - 1);

    floatx4 acc[4][TW];
#pragma unroll
    for (int rt = 0; rt < 4; rt++)
#pragma unroll
        for (int tt = 0; tt < TW; tt++) acc[rt][tt] = (floatx4){0.f, 0.f, 0.f, 0.f};

    constexpr int KSTEPS = KTEMP / 32;
#pragma unroll
    for (int ks = 0; ks < KSTEPS; ks++) {
        const int k0 = ks * 32;
        bf16x8 ah[4], alo_[4], bh[TW], bl_[TW];
#pragma unroll
        for (int rt = 0; rt < 4; rt++) {
            const size_t off = (size_t)arow[rt] * KTEMP + k0 + kq;
            ah[rt] = *(const bf16x8*)(Ahi + off);
            alo_[rt] = *(const bf16x8*)(Alo + off);
        }
#pragma unroll
        for (int tt = 0; tt < TW; tt++) {
            const size_t off = (size_t)(wc + tt * 16 + l15) * KTEMP + k0 + kq;
            bh[tt] = *(const bf16x8*)(Bhi + off);
            bl_[tt] = *(const bf16x8*)(Blo + off);
        }
#pragma unroll
        for (int rt = 0; rt < 4; rt++)
#pragma unroll
            for (int tt = 0; tt < TW; tt++) {
                acc[rt][tt] = __builtin_amdgcn_mfma_f32_16x16x32_bf16(ah[rt], bh[tt], acc[rt][tt], 0, 0, 0);
                acc[rt][tt] = __builtin_amdgcn_mfma_f32_16x16x32_bf16(alo_[rt], bh[tt], acc[rt][tt], 0, 0, 0);
                acc[rt][tt] = __builtin_amdgcn_mfma_f32_16x16x32_bf16(ah[rt], bl_[tt], acc[rt][tt], 0, 0, 0);
            }
    }

    // C/D layout: col = lane&15, row(in tile) = q*4 + reg  [m89/m91]
    float aLp[4][4], aRp[4][4];
    if constexpr (ALPHA) {
#pragma unroll
        for (int rt = 0; rt < 4; rt++)
#pragma unroll
            for (int r = 0; r < 4; r++) { aLp[rt][r] = 0.f; aRp[rt][r] = 0.f; }
    }

#pragma unroll
    for (int rt = 0; rt < 4; rt++) {
        const int rb = mbase + rt * 16 + q * 4;
#pragma unroll
        for (int tt = 0; tt < TW; tt++) {
            const int gcol = wc + tt * 16 + l15;
            float atlv = 0.f, atrv = 0.f;
            if constexpr (ALPHA) { atlv = attl[gcol]; atrv = attr[gcol]; }
#pragma unroll
            for (int r = 0; r < 4; r++) {
                float v = acc[rt][tt][r];
                if constexpr (BIAS) v += bias[gcol];
                if constexpr (ALPHA) { aLp[rt][r] += v * atlv; aRp[rt][r] += v * atrv; }
                const int grow = rb + r;
                if (grow < M) {
                    if constexpr (OMODE == 1) {
                        __bf16 h = (__bf16)v;
                        Chi[(size_t)grow * O + gcol] = h;
                        Clo[(size_t)grow * O + gcol] = (__bf16)(v - (float)h);
                    } else if constexpr (OMODE == 2) {
                        Cf16[(size_t)grow * O + gcol] = (_Float16)v;
                    } else {
                        C[(size_t)grow * O + gcol] = v;
                    }
                }
            }
        }
    }

    if constexpr (ALPHA) {
        __shared__ float sAL[4][64], sAR[4][64];
#pragma unroll
        for (int rt = 0; rt < 4; rt++)
#pragma unroll
            for (int r = 0; r < 4; r++) {
                float vl = aLp[rt][r], vr = aRp[rt][r];
                vl += __shfl_xor(vl, 1); vl += __shfl_xor(vl, 2);
                vl += __shfl_xor(vl, 4); vl += __shfl_xor(vl, 8);
                vr += __shfl_xor(vr, 1); vr += __shfl_xor(vr, 2);
                vr += __shfl_xor(vr, 4); vr += __shfl_xor(vr, 8);
                if (l15 == 0) {
                    sAL[wave][rt * 16 + q * 4 + r] = vl;
                    sAR[wave][rt * 16 + q * 4 + r] = vr;
                }
            }
        __syncthreads();
        if (tid < 64) {
            const int grow = mbase + tid;
            if (grow < M) {
                al[2 * grow]     = sAL[0][tid] + sAL[1][tid];
                al[2 * grow + 1] = sAL[2][tid] + sAL[3][tid];
                ar[2 * grow]     = sAR[0][tid] + sAR[1][tid];
                ar[2 * grow + 1] = sAR[2][tid] + sAR[3][tid];
            }
        }
    }
}

// ---------------------------------------------------------------------------
// CSR build
// ---------------------------------------------------------------------------
__device__ __forceinline__ int edge_src(const int* ei, int E, int e, int is64) {
    return is64 ? ei[2 * (size_t)e] : ei[e];
}
__device__ __forceinline__ int edge_dst(const int* ei, int E, int e, int is64) {
    return is64 ? ei[2 * (size_t)E + 2 * (size_t)e] : ei[(size_t)E + e];
}

__global__ void count_kernel(const int* __restrict__ ei, int E,
                             const int* __restrict__ flags, int* __restrict__ counts) {
    int e = blockIdx.x * blockDim.x + threadIdx.x;
    if (e < E) atomicAdd(&counts[edge_dst(ei, E, e, flags[1])], 1);
}

__global__ __launch_bounds__(1024) void scan1_kernel(const int* __restrict__ counts,
                                                     int* __restrict__ incl,
                                                     int* __restrict__ bsum, int N) {
    __shared__ int tmp[1024];
    const int t = threadIdx.x;
    const int i = blockIdx.x * 1024 + t;
    int v = (i < N) ? counts[i] : 0;
    tmp[t] = v;
    __syncthreads();
    for (int off = 1; off < 1024; off <<= 1) {
        int x = (t >= off) ? tmp[t - off] : 0;
        __syncthreads();
        tmp[t] += x;
        __syncthreads();
    }
    if (i < N) incl[i] = tmp[t];
    if (t == 1023) bsum[blockIdx.x] = tmp[1023];
}

__global__ void scan2_kernel(const int* __restrict__ bsum, int* __restrict__ boffs,
                             int nb, int* __restrict__ row_ptr, int N) {
    if (threadIdx.x == 0) {
        int run = 0;
        for (int b = 0; b < nb; b++) { boffs[b] = run; run += bsum[b]; }
        row_ptr[N] = run;
    }
}

__global__ void scan3_kernel(const int* __restrict__ incl, const int* __restrict__ counts,
                             const int* __restrict__ boffs, int* __restrict__ row_ptr,
                             int* __restrict__ fill, int N) {
    int i = blockIdx.x * blockDim.x + threadIdx.x;
    if (i < N) {
        int v = boffs[i >> 10] + incl[i] - counts[i];
        row_ptr[i] = v;
        fill[i] = v;
    }
}

__global__ void scatter_kernel(const int* __restrict__ ei, int E,
                               const int* __restrict__ flags,
                               int* __restrict__ fill, int* __restrict__ esrc) {
    int e = blockIdx.x * blockDim.x + threadIdx.x;
    if (e < E) {
        int is64 = flags[1];
        int s = edge_src(ei, E, e, is64);
        int d = edge_dst(ei, E, e, is64);
        int pos = atomicAdd(&fill[d], 1);
        esrc[pos] = s;
    }
}

// ---------------------------------------------------------------------------
// Fused segment softmax + aggregation, wave-per-node, online softmax.
// Chunk = 64 edges: lane j holds logits of edge base+j; shfl max-reduce;
// running (m,l) rescale. Gather: half-wave per edge (16 B/lane, 2 edges/iter),
// weights+src broadcast via shfl. Epilogue: cross-half combine, 1/l, relu,
// bf16 hi/lo split.
// ---------------------------------------------------------------------------
__global__ __launch_bounds__(256) void agg_fused_kernel(
    const _Float16* __restrict__ xl,
    const float* __restrict__ al, const float* __restrict__ ar,
    const int* __restrict__ row_ptr, const int* __restrict__ esrc,
    __bf16* __restrict__ hhi, __bf16* __restrict__ hlo, int N) {
    const int wid = (blockIdx.x * 256 + threadIdx.x) >> 6;   // node id
    if (wid >= N) return;
    const int lane = threadIdx.x & 63;
    const int half = lane >> 5;          // which edge of the pair
    const int c8 = (lane & 31) * 8;      // my 8-column base
    const int hsel = c8 >> 7;            // head of my columns
    const int s0 = row_ptr[wid], e0 = row_ptr[wid + 1];
    const float ar0 = ar[2 * wid], ar1 = ar[2 * wid + 1];

    float acc[8];
#pragma unroll
    for (int c = 0; c < 8; c++) acc[c] = 0.f;
    float m0 = -INFINITY, m1 = -INFINITY, l0 = 0.f, l1 = 0.f;

    for (int base = s0; base < e0; base += 64) {
        const int n = min(64, e0 - base);
        int s = 0;
        float lg0 = -INFINITY, lg1 = -INFINITY;
        if (lane < n) {
            s = esrc[base + lane];
            float2 av = *(const float2*)(al + 2 * s);
            lg0 = av.x + ar0; lg0 = lg0 > 0.f ? lg0 : NEG_SLOPE * lg0;
            lg1 = av.y + ar1; lg1 = lg1 > 0.f ? lg1 : NEG_SLOPE * lg1;
        }
        float cm0 = lg0, cm1 = lg1;
#pragma unroll
        for (int off = 1; off < 64; off <<= 1) {
            cm0 = fmaxf(cm0, __shfl_xor(cm0, off));
            cm1 = fmaxf(cm1, __shfl_xor(cm1, off));
        }
        const float nm0 = fmaxf(m0, cm0), nm1 = fmaxf(m1, cm1);
        const float sc0 = __expf(m0 - nm0), sc1 = __expf(m1 - nm1);
        m0 = nm0; m1 = nm1;
        float p0 = 0.f, p1 = 0.f;
        if (lane < n) { p0 = __expf(lg0 - nm0); p1 = __expf(lg1 - nm1); }
        l0 = l0 * sc0 + p0;
        l1 = l1 * sc1 + p1;
        const float asc = hsel ? sc1 : sc0;
#pragma unroll
        for (int c = 0; c < 8; c++) acc[c] *= asc;

#pragma unroll 4
        for (int j = 0; j < n; j += 2) {
            const int jj = j + half;
            const float w0 = __shfl(p0, jj);
            const float w1 = __shfl(p1, jj);
            const int ss = __shfl(s, jj);
            if (jj < n) {
                const float wv = hsel ? w1 : w0;
                half8v xv = *(const half8v*)(xl + (size_t)ss * HC + c8);
#pragma unroll
                for (int c = 0; c < 8; c++) acc[c] += wv * (float)xv[c];
            }
        }
    }

    // total denominators
#pragma unroll
    for (int off = 1; off < 64; off <<= 1) {
        l0 += __shfl_xor(l0, off);
        l1 += __shfl_xor(l1, off);
    }
    const float winv = 1.f / ((hsel ? l1 : l0) + SOFTMAX_EPS);

    // combine the two half-wave edge partitions, normalize, relu
#pragma unroll
    for (int c = 0; c < 8; c++) {
        acc[c] += __shfl_xor(acc[c], 32);
        acc[c] = fmaxf(acc[c] * winv, 0.f);
    }
    if (half == 0) {
        bf16x8 vh, vl;
#pragma unroll
        for (int c = 0; c < 8; c++) {
            __bf16 h = (__bf16)acc[c];
            vh[c] = h;
            vl[c] = (__bf16)(acc[c] - (float)h);
        }
        const size_t bo = (size_t)wid * HC + c8;
        *(bf16x8*)(hhi + bo) = vh;
        *(bf16x8*)(hlo + bo) = vl;
    }
}

// ---------------------------------------------------------------------------
extern "C" void kernel_launch(void* const* d_in, const int* in_sizes, int n_in,
                              void* d_out, int out_size, void* d_ws, size_t ws_size,
                              hipStream_t stream) {
    const int D = 128;
    const int N = in_sizes[0] / D;   // 50000
    const int E = in_sizes[1] / 2;   // 800000
    const int* ei = (const int*)d_in[1];

    char* w = (char*)d_ws;
    auto alloc = [&](size_t bytes) {
        void* p = w;
        w += (bytes + 255) & ~(size_t)255;
        return p;
    };
    int*      flags  = (int*)     alloc(256);
    __bf16*   x_hi   = (__bf16*)  alloc((size_t)N * D * 2);
    __bf16*   x_lo   = (__bf16*)  alloc((size_t)N * D * 2);
    __bf16*   W1h    = (__bf16*)  alloc((size_t)in_sizes[2] * 2);
    __bf16*   W1l    = (__bf16*)  alloc((size_t)in_sizes[2] * 2);
    __bf16*   W2h    = (__bf16*)  alloc((size_t)in_sizes[5] * 2);
    __bf16*   W2l    = (__bf16*)  alloc((size_t)in_sizes[5] * 2);
    __bf16*   Wp1h   = (__bf16*)  alloc((size_t)in_sizes[8] * 2);
    __bf16*   Wp1l   = (__bf16*)  alloc((size_t)in_sizes[8] * 2);
    __bf16*   Wp2h   = (__bf16*)  alloc((size_t)in_sizes[10] * 2);
    __bf16*   Wp2l   = (__bf16*)  alloc((size_t)in_sizes[10] * 2);
    float*    atl1   = (float*)   alloc((size_t)in_sizes[3] * 4);
    float*    atr1   = (float*)   alloc((size_t)in_sizes[4] * 4);
    float*    atl2   = (float*)   alloc((size_t)in_sizes[6] * 4);
    float*    atr2   = (float*)   alloc((size_t)in_sizes[7] * 4);
    float*    bfp1   = (float*)   alloc((size_t)in_sizes[9] * 4);
    float*    bfp2   = (float*)   alloc((size_t)in_sizes[11] * 4);
    _Float16* xl16   = (_Float16*)alloc((size_t)N * HC * 2);   // 25.6 MB
    __bf16*   h_hi   = (__bf16*)  alloc((size_t)N * HC * 2);
    __bf16*   h_lo   = (__bf16*)  alloc((size_t)N * HC * 2);
    float*    al     = (float*)   alloc((size_t)N * 2 * 4);
    float*    ar     = (float*)   alloc((size_t)N * 2 * 4);
    int*      counts = (int*)     alloc((size_t)N * 4);
    int*      incl   = (int*)     alloc((size_t)N * 4);
    int*      row_ptr= (int*)     alloc((size_t)(N + 1) * 4);
    int*      fill   = (int*)     alloc((size_t)N * 4);
    int*      bsum   = (int*)     alloc(1024);
    int*      boffs  = (int*)     alloc(1024);
    int*      esrc   = (int*)     alloc((size_t)E * 4);

    const int EB = (E + 255) / 256;
    const int GM = (N + 63) / 64;
    const int NB1024 = (N + 1023) / 1024;
    const int AGG_B = (N + 3) / 4;   // 4 waves/block, wave per node

    // 0. dtype sniff + canonicalize
    detect_kernel<<<1, 256, 0, stream>>>((const uint32_t*)d_in[0], (const uint32_t*)d_in[1], flags);
    conv_small_kernel<<<1, 256, 0, stream>>>(d_in[3], atl1, in_sizes[3],
                                             d_in[4], atr1, in_sizes[4],
                                             d_in[6], atl2, in_sizes[6],
                                             d_in[7], atr2, in_sizes[7],
                                             d_in[9], bfp1, in_sizes[9],
                                             d_in[11], bfp2, in_sizes[11], flags);
    split_kernel<<<(in_sizes[0] + 255) / 256, 256, 0, stream>>>(d_in[0], x_hi, x_lo, in_sizes[0], flags);
    {
        int nt = in_sizes[2] + in_sizes[5] + in_sizes[8] + in_sizes[10];
        split4_kernel<<<(nt + 255) / 256, 256, 0, stream>>>(
            d_in[2], W1h, W1l, in_sizes[2],
            d_in[5], W2h, W2l, in_sizes[5],
            d_in[8], Wp1h, Wp1l, in_sizes[8],
            d_in[10], Wp2h, Wp2l, in_sizes[10], flags);
    }

    // 1. CSR build
    hipMemsetAsync(counts, 0, (size_t)N * 4, stream);
    count_kernel<<<EB, 256, 0, stream>>>(ei, E, flags, counts);
    scan1_kernel<<<NB1024, 1024, 0, stream>>>(counts, incl, bsum, N);
    scan2_kernel<<<1, 64, 0, stream>>>(bsum, boffs, NB1024, row_ptr, N);
    scan3_kernel<<<(N + 255) / 256, 256, 0, stream>>>(incl, counts, boffs, row_ptr, fill, N);
    scatter_kernel<<<EB, 256, 0, stream>>>(ei, E, flags, fill, esrc);

    // 2. GAT layer 1: xl16 = x@W1^T (fp16 out, alpha fused), K=128
    gemm_bt<128, 16, false, true, 2><<<GM, 256, 0, stream>>>(
        x_hi, x_lo, W1h, W1l, nullptr, nullptr, nullptr, nullptr, xl16, atl1, atr1, al, ar, N);
    agg_fused_kernel<<<AGG_B, 256, 0, stream>>>(xl16, al, ar, row_ptr, esrc, h_hi, h_lo, N);

    // 3. GAT layer 2: xl16 = h1@W2^T (fp16 out, alpha fused), K=256
    gemm_bt<256, 16, false, true, 2><<<GM, 256, 0, stream>>>(
        h_hi, h_lo, W2h, W2l, nullptr, nullptr, nullptr, nullptr, xl16, atl2, atr2, al, ar, N);
    agg_fused_kernel<<<AGG_B, 256, 0, stream>>>(xl16, al, ar, row_ptr, esrc, h_hi, h_lo, N);

    // 4. projections: p = h2@Wp1^T + bp1 (K=256, O=128, bf16 hi/lo out)
    gemm_bt<256, 8, true, false, 1><<<GM, 256, 0, stream>>>(
        h_hi, h_lo, Wp1h, Wp1l, bfp1, nullptr, x_hi, x_lo, nullptr, nullptr, nullptr, nullptr, nullptr, N);
    // out = p@Wp2^T + bp2 (K=128, O=128) -> f32 d_out
    gemm_bt<128, 8, true, false, 0><<<GM, 256, 0, stream>>>(
        x_hi, x_lo, Wp2h, Wp2l, bfp2, (float*)d_out, nullptr, nullptr, nullptr, nullptr, nullptr, nullptr, nullptr, N);
}

// Round 8
// 525.859 us; speedup vs baseline: 1.9604x; 1.0079x over previous
//
#include <hip/hip_runtime.h>
#include <hip/hip_bf16.h>
#include <stdint.h>

// TermEncoder GAT: N=50000, E=800000, D=128, H=2, C=128, HC=256
// R8: GEMM register double-buffer prefetch. r7: gemm<256,16> 73us, MfmaUtil
// 10%, VGPR 96 -> compiler had no registers for cross-k prefetch. Explicit
// bufA/bufB[2] + launch_bounds(256,2). Everything else unchanged from r7.
#define HC 256
#define NEG_SLOPE 0.2f
#define SOFTMAX_EPS 1e-16f

typedef __bf16 bf16x8 __attribute__((ext_vector_type(8)));
typedef float floatx4 __attribute__((ext_vector_type(4)));
typedef _Float16 half8v __attribute__((ext_vector_type(8)));

// ---------------------------------------------------------------------------
// dtype sniffing: flags[0]=float-is-bf16, flags[1]=edge-index-is-int64.
// ---------------------------------------------------------------------------
__global__ void detect_kernel(const uint32_t* __restrict__ xw,
                              const uint32_t* __restrict__ ew,
                              int* __restrict__ flags) {
    __shared__ int cnt_bf16, cnt_odd_nz;
    const int t = threadIdx.x;
    if (t == 0) { cnt_bf16 = 0; cnt_odd_nz = 0; }
    __syncthreads();
    uint32_t w = xw[t];
    uint32_t ef = ((w & 0xFFFFu) >> 7) & 0xFFu;
    if (ef >= 90u && ef <= 135u) atomicAdd(&cnt_bf16, 1);
    if (t < 64 && ew[2 * t + 1] != 0u) atomicAdd(&cnt_odd_nz, 1);
    __syncthreads();
    if (t == 0) {
        flags[0] = (cnt_bf16 > 192) ? 1 : 0;
        flags[1] = (cnt_odd_nz == 0) ? 1 : 0;
    }
}

__device__ __forceinline__ float in_load(const void* p, int i, int is_bf16) {
    return is_bf16 ? (float)((const __bf16*)p)[i] : ((const float*)p)[i];
}

__global__ void conv_small_kernel(const void* a0, float* o0, int n0,
                                  const void* a1, float* o1, int n1,
                                  const void* a2, float* o2, int n2,
                                  const void* a3, float* o3, int n3,
                                  const void* a4, float* o4, int n4,
                                  const void* a5, float* o5, int n5,
                                  const int* __restrict__ flags) {
    const int t = threadIdx.x;
    const int fb = flags[0];
    if (t < n0) o0[t] = in_load(a0, t, fb);
    if (t < n1) o1[t] = in_load(a1, t, fb);
    if (t < n2) o2[t] = in_load(a2, t, fb);
    if (t < n3) o3[t] = in_load(a3, t, fb);
    if (t < n4) o4[t] = in_load(a4, t, fb);
    if (t < n5) o5[t] = in_load(a5, t, fb);
}

__global__ void split_kernel(const void* __restrict__ in, __bf16* __restrict__ hi,
                             __bf16* __restrict__ lo, int n, const int* __restrict__ flags) {
    int i = blockIdx.x * blockDim.x + threadIdx.x;
    if (i >= n) return;
    float v = in_load(in, i, flags[0]);
    __bf16 h = (__bf16)v;
    hi[i] = h;
    lo[i] = (__bf16)(v - (float)h);
}

__global__ void split4_kernel(const void* i0, __bf16* h0, __bf16* l0, int n0,
                              const void* i1, __bf16* h1, __bf16* l1, int n1,
                              const void* i2, __bf16* h2, __bf16* l2, int n2,
                              const void* i3, __bf16* h3, __bf16* l3, int n3,
                              const int* __restrict__ flags) {
    int idx = blockIdx.x * blockDim.x + threadIdx.x;
    const void* in;
    __bf16 *ph, *pl;
    int off = idx;
    if (off < n0)      { in = i0; ph = h0; pl = l0; }
    else if ((off -= n0) < n1) { in = i1; ph = h1; pl = l1; }
    else if ((off -= n1) < n2) { in = i2; ph = h2; pl = l2; }
    else if ((off -= n2) < n3) { in = i3; ph = h3; pl = l3; }
    else return;
    float v = in_load(in, off, flags[0]);
    __bf16 h = (__bf16)v;
    ph[off] = h;
    pl[off] = (__bf16)(v - (float)h);
}

// ---------------------------------------------------------------------------
// GEMM: C[M,O] = A[M,KTEMP]@B[O,KTEMP]^T (+bias), pre-split bf16 hi/lo.
// Wave w owns O/4 cols; explicit register double-buffer: k+1's 16 fragment
// loads issue before k's MFMA burst (cross-k latency hiding). launch_bounds
// (256,2) raises VGPR cap to 256 for the second buffer.
// OMODE: 0=f32, 1=bf16 hi/lo split, 2=fp16.
// ---------------------------------------------------------------------------
template <int KTEMP, int OTILES, bool BIAS, bool ALPHA, int OMODE>
__global__ __launch_bounds__(256, 2) void gemm_bt(
    const __bf16* __restrict__ Ahi, const __bf16* __restrict__ Alo,
    const __bf16* __restrict__ Bhi, const __bf16* __restrict__ Blo,
    const float* __restrict__ bias,
    float* __restrict__ C, __bf16* __restrict__ Chi, __bf16* __restrict__ Clo,
    _Float16* __restrict__ Cf16,
    const float* __restrict__ attl, const float* __restrict__ attr,
    float* __restrict__ al, float* __restrict__ ar,
    int M) {
    static_assert(!ALPHA || OTILES == 16, "alpha fusion assumes O=256");
    constexpr int TW = OTILES / 4;
    constexpr int O = OTILES * 16;
    const int tid = threadIdx.x;
    const int lane = tid & 63;
    const int wave = tid >> 6;
    const int mbase = blockIdx.x * 64;
    const int l15 = lane & 15;
    const int q = lane >> 4;
    const int kq = q * 8;
    const int wc = wave * TW * 16;

    int arow[4];
#pragma unroll
    for (int rt = 0; rt < 4; rt++) arow[rt] = min(mbase + rt * 16 + l15, M - 1);

    floatx4 acc[4][TW];
#pragma unroll
    for (int rt = 0; rt < 4; rt++)
#pragma unroll
        for (int tt = 0; tt < TW; tt++) acc[rt][tt] = (floatx4){0.f, 0.f, 0.f, 0.f};

    constexpr int KSTEPS = KTEMP / 32;
    bf16x8 bufA[2][8];        // [buf][rt:hi 0..3, lo 4..7]
    bf16x8 bufB[2][2 * TW];   // [buf][tt:hi 0..TW-1, lo TW..2TW-1]

    auto load_k = [&](int ks, int b) {
        const int k0 = ks * 32;
#pragma unroll
        for (int rt = 0; rt < 4; rt++) {
            const size_t off = (size_t)arow[rt] * KTEMP + k0 + kq;
            bufA[b][rt] = *(const bf16x8*)(Ahi + off);
            bufA[b][4 + rt] = *(const bf16x8*)(Alo + off);
        }
#pragma unroll
        for (int tt = 0; tt < TW; tt++) {
            const size_t off = (size_t)(wc + tt * 16 + l15) * KTEMP + k0 + kq;
            bufB[b][tt] = *(const bf16x8*)(Bhi + off);
            bufB[b][TW + tt] = *(const bf16x8*)(Blo + off);
        }
    };

    load_k(0, 0);
#pragma unroll
    for (int ks = 0; ks < KSTEPS; ks++) {
        const int cur = ks & 1;
        if (ks + 1 < KSTEPS) load_k(ks + 1, cur ^ 1);
#pragma unroll
        for (int rt = 0; rt < 4; rt++)
#pragma unroll
            for (int tt = 0; tt < TW; tt++) {
                acc[rt][tt] = __builtin_amdgcn_mfma_f32_16x16x32_bf16(bufA[cur][rt], bufB[cur][tt], acc[rt][tt], 0, 0, 0);
                acc[rt][tt] = __builtin_amdgcn_mfma_f32_16x16x32_bf16(bufA[cur][4 + rt], bufB[cur][tt], acc[rt][tt], 0, 0, 0);
                acc[rt][tt] = __builtin_amdgcn_mfma_f32_16x16x32_bf16(bufA[cur][rt], bufB[cur][TW + tt], acc[rt][tt], 0, 0, 0);
            }
    }

    // C/D layout: col = lane&15, row(in tile) = q*4 + reg  [m89/m91]
    float aLp[4][4], aRp[4][4];
    if constexpr (ALPHA) {
#pragma unroll
        for (int rt = 0; rt < 4; rt++)
#pragma unroll
            for (int r = 0; r < 4; r++) { aLp[rt][r] = 0.f; aRp[rt][r] = 0.f; }
    }

#pragma unroll
    for (int rt = 0; rt < 4; rt++) {
        const int rb = mbase + rt * 16 + q * 4;
#pragma unroll
        for (int tt = 0; tt < TW; tt++) {
            const int gcol = wc + tt * 16 + l15;
            float atlv = 0.f, atrv = 0.f;
            if constexpr (ALPHA) { atlv = attl[gcol]; atrv = attr[gcol]; }
#pragma unroll
            for (int r = 0; r < 4; r++) {
                float v = acc[rt][tt][r];
                if constexpr (BIAS) v += bias[gcol];
                if constexpr (ALPHA) { aLp[rt][r] += v * atlv; aRp[rt][r] += v * atrv; }
                const int grow = rb + r;
                if (grow < M) {
                    if constexpr (OMODE == 1) {
                        __bf16 h = (__bf16)v;
                        Chi[(size_t)grow * O + gcol] = h;
                        Clo[(size_t)grow * O + gcol] = (__bf16)(v - (float)h);
                    } else if constexpr (OMODE == 2) {
                        Cf16[(size_t)grow * O + gcol] = (_Float16)v;
                    } else {
                        C[(size_t)grow * O + gcol] = v;
                    }
                }
            }
        }
    }

    if constexpr (ALPHA) {
        __shared__ float sAL[4][64], sAR[4][64];
#pragma unroll
        for (int rt = 0; rt < 4; rt++)
#pragma unroll
            for (int r = 0; r < 4; r++) {
                float vl = aLp[rt][r], vr = aRp[rt][r];
                vl += __shfl_xor(vl, 1); vl += __shfl_xor(vl, 2);
                vl += __shfl_xor(vl, 4); vl += __shfl_xor(vl, 8);
                vr += __shfl_xor(vr, 1); vr += __shfl_xor(vr, 2);
                vr += __shfl_xor(vr, 4); vr += __shfl_xor(vr, 8);
                if (l15 == 0) {
                    sAL[wave][rt * 16 + q * 4 + r] = vl;
                    sAR[wave][rt * 16 + q * 4 + r] = vr;
                }
            }
        __syncthreads();
        if (tid < 64) {
            const int grow = mbase + tid;
            if (grow < M) {
                al[2 * grow]     = sAL[0][tid] + sAL[1][tid];
                al[2 * grow + 1] = sAL[2][tid] + sAL[3][tid];
                ar[2 * grow]     = sAR[0][tid] + sAR[1][tid];
                ar[2 * grow + 1] = sAR[2][tid] + sAR[3][tid];
            }
        }
    }
}

// ---------------------------------------------------------------------------
// CSR build
// ---------------------------------------------------------------------------
__device__ __forceinline__ int edge_src(const int* ei, int E, int e, int is64) {
    return is64 ? ei[2 * (size_t)e] : ei[e];
}
__device__ __forceinline__ int edge_dst(const int* ei, int E, int e, int is64) {
    return is64 ? ei[2 * (size_t)E + 2 * (size_t)e] : ei[(size_t)E + e];
}

__global__ void count_kernel(const int* __restrict__ ei, int E,
                             const int* __restrict__ flags, int* __restrict__ counts) {
    int e = blockIdx.x * blockDim.x + threadIdx.x;
    if (e < E) atomicAdd(&counts[edge_dst(ei, E, e, flags[1])], 1);
}

__global__ __launch_bounds__(1024) void scan1_kernel(const int* __restrict__ counts,
                                                     int* __restrict__ incl,
                                                     int* __restrict__ bsum, int N) {
    __shared__ int tmp[1024];
    const int t = threadIdx.x;
    const int i = blockIdx.x * 1024 + t;
    int v = (i < N) ? counts[i] : 0;
    tmp[t] = v;
    __syncthreads();
    for (int off = 1; off < 1024; off <<= 1) {
        int x = (t >= off) ? tmp[t - off] : 0;
        __syncthreads();
        tmp[t] += x;
        __syncthreads();
    }
    if (i < N) incl[i] = tmp[t];
    if (t == 1023) bsum[blockIdx.x] = tmp[1023];
}

__global__ void scan2_kernel(const int* __restrict__ bsum, int* __restrict__ boffs,
                             int nb, int* __restrict__ row_ptr, int N) {
    if (threadIdx.x == 0) {
        int run = 0;
        for (int b = 0; b < nb; b++) { boffs[b] = run; run += bsum[b]; }
        row_ptr[N] = run;
    }
}

__global__ void scan3_kernel(const int* __restrict__ incl, const int* __restrict__ counts,
                             const int* __restrict__ boffs, int* __restrict__ row_ptr,
                             int* __restrict__ fill, int N) {
    int i = blockIdx.x * blockDim.x + threadIdx.x;
    if (i < N) {
        int v = boffs[i >> 10] + incl[i] - counts[i];
        row_ptr[i] = v;
        fill[i] = v;
    }
}

__global__ void scatter_kernel(const int* __restrict__ ei, int E,
                               const int* __restrict__ flags,
                               int* __restrict__ fill, int* __restrict__ esrc) {
    int e = blockIdx.x * blockDim.x + threadIdx.x;
    if (e < E) {
        int is64 = flags[1];
        int s = edge_src(ei, E, e, is64);
        int d = edge_dst(ei, E, e, is64);
        int pos = atomicAdd(&fill[d], 1);
        esrc[pos] = s;
    }
}

// ---------------------------------------------------------------------------
// Fused segment softmax + aggregation, wave-per-node, online softmax.
// ---------------------------------------------------------------------------
__global__ __launch_bounds__(256) void agg_fused_kernel(
    const _Float16* __restrict__ xl,
    const float* __restrict__ al, const float* __restrict__ ar,
    const int* __restrict__ row_ptr, const int* __restrict__ esrc,
    __bf16* __restrict__ hhi, __bf16* __restrict__ hlo, int N) {
    const int wid = (blockIdx.x * 256 + threadIdx.x) >> 6;   // node id
    if (wid >= N) return;
    const int lane = threadIdx.x & 63;
    const int half = lane >> 5;          // which edge of the pair
    const int c8 = (lane & 31) * 8;      // my 8-column base
    const int hsel = c8 >> 7;            // head of my columns
    const int s0 = row_ptr[wid], e0 = row_ptr[wid + 1];
    const float ar0 = ar[2 * wid], ar1 = ar[2 * wid + 1];

    float acc[8];
#pragma unroll
    for (int c = 0; c < 8; c++) acc[c] = 0.f;
    float m0 = -INFINITY, m1 = -INFINITY, l0 = 0.f, l1 = 0.f;

    for (int base = s0; base < e0; base += 64) {
        const int n = min(64, e0 - base);
        int s = 0;
        float lg0 = -INFINITY, lg1 = -INFINITY;
        if (lane < n) {
            s = esrc[base + lane];
            float2 av = *(const float2*)(al + 2 * s);
            lg0 = av.x + ar0; lg0 = lg0 > 0.f ? lg0 : NEG_SLOPE * lg0;
            lg1 = av.y + ar1; lg1 = lg1 > 0.f ? lg1 : NEG_SLOPE * lg1;
        }
        float cm0 = lg0, cm1 = lg1;
#pragma unroll
        for (int off = 1; off < 64; off <<= 1) {
            cm0 = fmaxf(cm0, __shfl_xor(cm0, off));
            cm1 = fmaxf(cm1, __shfl_xor(cm1, off));
        }
        const float nm0 = fmaxf(m0, cm0), nm1 = fmaxf(m1, cm1);
        const float sc0 = __expf(m0 - nm0), sc1 = __expf(m1 - nm1);
        m0 = nm0; m1 = nm1;
        float p0 = 0.f, p1 = 0.f;
        if (lane < n) { p0 = __expf(lg0 - nm0); p1 = __expf(lg1 - nm1); }
        l0 = l0 * sc0 + p0;
        l1 = l1 * sc1 + p1;
        const float asc = hsel ? sc1 : sc0;
#pragma unroll
        for (int c = 0; c < 8; c++) acc[c] *= asc;

#pragma unroll 4
        for (int j = 0; j < n; j += 2) {
            const int jj = j + half;
            const float w0 = __shfl(p0, jj);
            const float w1 = __shfl(p1, jj);
            const int ss = __shfl(s, jj);
            if (jj < n) {
                const float wv = hsel ? w1 : w0;
                half8v xv = *(const half8v*)(xl + (size_t)ss * HC + c8);
#pragma unroll
                for (int c = 0; c < 8; c++) acc[c] += wv * (float)xv[c];
            }
        }
    }

    // total denominators
#pragma unroll
    for (int off = 1; off < 64; off <<= 1) {
        l0 += __shfl_xor(l0, off);
        l1 += __shfl_xor(l1, off);
    }
    const float winv = 1.f / ((hsel ? l1 : l0) + SOFTMAX_EPS);

#pragma unroll
    for (int c = 0; c < 8; c++) {
        acc[c] += __shfl_xor(acc[c], 32);
        acc[c] = fmaxf(acc[c] * winv, 0.f);
    }
    if (half == 0) {
        bf16x8 vh, vl;
#pragma unroll
        for (int c = 0; c < 8; c++) {
            __bf16 h = (__bf16)acc[c];
            vh[c] = h;
            vl[c] = (__bf16)(acc[c] - (float)h);
        }
        const size_t bo = (size_t)wid * HC + c8;
        *(bf16x8*)(hhi + bo) = vh;
        *(bf16x8*)(hlo + bo) = vl;
    }
}

// ---------------------------------------------------------------------------
extern "C" void kernel_launch(void* const* d_in, const int* in_sizes, int n_in,
                              void* d_out, int out_size, void* d_ws, size_t ws_size,
                              hipStream_t stream) {
    const int D = 128;
    const int N = in_sizes[0] / D;   // 50000
    const int E = in_sizes[1] / 2;   // 800000
    const int* ei = (const int*)d_in[1];

    char* w = (char*)d_ws;
    auto alloc = [&](size_t bytes) {
        void* p = w;
        w += (bytes + 255) & ~(size_t)255;
        return p;
    };
    int*      flags  = (int*)     alloc(256);
    __bf16*   x_hi   = (__bf16*)  alloc((size_t)N * D * 2);
    __bf16*   x_lo   = (__bf16*)  alloc((size_t)N * D * 2);
    __bf16*   W1h    = (__bf16*)  alloc((size_t)in_sizes[2] * 2);
    __bf16*   W1l    = (__bf16*)  alloc((size_t)in_sizes[2] * 2);
    __bf16*   W2h    = (__bf16*)  alloc((size_t)in_sizes[5] * 2);
    __bf16*   W2l    = (__bf16*)  alloc((size_t)in_sizes[5] * 2);
    __bf16*   Wp1h   = (__bf16*)  alloc((size_t)in_sizes[8] * 2);
    __bf16*   Wp1l   = (__bf16*)  alloc((size_t)in_sizes[8] * 2);
    __bf16*   Wp2h   = (__bf16*)  alloc((size_t)in_sizes[10] * 2);
    __bf16*   Wp2l   = (__bf16*)  alloc((size_t)in_sizes[10] * 2);
    float*    atl1   = (float*)   alloc((size_t)in_sizes[3] * 4);
    float*    atr1   = (float*)   alloc((size_t)in_sizes[4] * 4);
    float*    atl2   = (float*)   alloc((size_t)in_sizes[6] * 4);
    float*    atr2   = (float*)   alloc((size_t)in_sizes[7] * 4);
    float*    bfp1   = (float*)   alloc((size_t)in_sizes[9] * 4);
    float*    bfp2   = (float*)   alloc((size_t)in_sizes[11] * 4);
    _Float16* xl16   = (_Float16*)alloc((size_t)N * HC * 2);   // 25.6 MB
    __bf16*   h_hi   = (__bf16*)  alloc((size_t)N * HC * 2);
    __bf16*   h_lo   = (__bf16*)  alloc((size_t)N * HC * 2);
    float*    al     = (float*)   alloc((size_t)N * 2 * 4);
    float*    ar     = (float*)   alloc((size_t)N * 2 * 4);
    int*      counts = (int*)     alloc((size_t)N * 4);
    int*      incl   = (int*)     alloc((size_t)N * 4);
    int*      row_ptr= (int*)     alloc((size_t)(N + 1) * 4);
    int*      fill   = (int*)     alloc((size_t)N * 4);
    int*      bsum   = (int*)     alloc(1024);
    int*      boffs  = (int*)     alloc(1024);
    int*      esrc   = (int*)     alloc((size_t)E * 4);

    const int EB = (E + 255) / 256;
    const int GM = (N + 63) / 64;
    const int NB1024 = (N + 1023) / 1024;
    const int AGG_B = (N + 3) / 4;   // 4 waves/block, wave per node

    // 0. dtype sniff + canonicalize
    detect_kernel<<<1, 256, 0, stream>>>((const uint32_t*)d_in[0], (const uint32_t*)d_in[1], flags);
    conv_small_kernel<<<1, 256, 0, stream>>>(d_in[3], atl1, in_sizes[3],
                                             d_in[4], atr1, in_sizes[4],
                                             d_in[6], atl2, in_sizes[6],
                                             d_in[7], atr2, in_sizes[7],
                                             d_in[9], bfp1, in_sizes[9],
                                             d_in[11], bfp2, in_sizes[11], flags);
    split_kernel<<<(in_sizes[0] + 255) / 256, 256, 0, stream>>>(d_in[0], x_hi, x_lo, in_sizes[0], flags);
    {
        int nt = in_sizes[2] + in_sizes[5] + in_sizes[8] + in_sizes[10];
        split4_kernel<<<(nt + 255) / 256, 256, 0, stream>>>(
            d_in[2], W1h, W1l, in_sizes[2],
            d_in[5], W2h, W2l, in_sizes[5],
            d_in[8], Wp1h, Wp1l, in_sizes[8],
            d_in[10], Wp2h, Wp2l, in_sizes[10], flags);
    }

    // 1. CSR build
    hipMemsetAsync(counts, 0, (size_t)N * 4, stream);
    count_kernel<<<EB, 256, 0, stream>>>(ei, E, flags, counts);
    scan1_kernel<<<NB1024, 1024, 0, stream>>>(counts, incl, bsum, N);
    scan2_kernel<<<1, 64, 0, stream>>>(bsum, boffs, NB1024, row_ptr, N);
    scan3_kernel<<<(N + 255) / 256, 256, 0, stream>>>(incl, counts, boffs, row_ptr, fill, N);
    scatter_kernel<<<EB, 256, 0, stream>>>(ei, E, flags, fill, esrc);

    // 2. GAT layer 1: xl16 = x@W1^T (fp16 out, alpha fused), K=128
    gemm_bt<128, 16, false, true, 2><<<GM, 256, 0, stream>>>(
        x_hi, x_lo, W1h, W1l, nullptr, nullptr, nullptr, nullptr, xl16, atl1, atr1, al, ar, N);
    agg_fused_kernel<<<AGG_B, 256, 0, stream>>>(xl16, al, ar, row_ptr, esrc, h_hi, h_lo, N);

    // 3. GAT layer 2: xl16 = h1@W2^T (fp16 out, alpha fused), K=256
    gemm_bt<256, 16, false, true, 2><<<GM, 256, 0, stream>>>(
        h_hi, h_lo, W2h, W2l, nullptr, nullptr, nullptr, nullptr, xl16, atl2, atr2, al, ar, N);
    agg_fused_kernel<<<AGG_B, 256, 0, stream>>>(xl16, al, ar, row_ptr, esrc, h_hi, h_lo, N);

    // 4. projections: p = h2@Wp1^T + bp1 (K=256, O=128, bf16 hi/lo out)
    gemm_bt<256, 8, true, false, 1><<<GM, 256, 0, stream>>>(
        h_hi, h_lo, Wp1h, Wp1l, bfp1, nullptr, x_hi, x_lo, nullptr, nullptr, nullptr, nullptr, nullptr, N);
    // out = p@Wp2^T + bp2 (K=128, O=128) -> f32 d_out
    gemm_bt<128, 8, true, false, 0><<<GM, 256, 0, stream>>>(
        x_hi, x_lo, Wp2h, Wp2l, bfp2, (float*)d_out, nullptr, nullptr, nullptr, nullptr, nullptr, nullptr, nullptr, N);
}

// Round 9
// 441.610 us; speedup vs baseline: 2.3345x; 1.1908x over previous
//
#include <hip/hip_runtime.h>
#include <hip/hip_bf16.h>
#include <stdint.h>

// TermEncoder GAT: N=50000, E=800000, D=128, H=2, C=128, HC=256
// R9: full fp16 pipeline. r8 lesson: compiler defeats register dbuf (VGPR
// 96->68, no gain). Instead cut the work: single fp16 MFMA (no hi/lo split)
// -> 8 loads + 16 MFMAs per k-step (was 16+48). fp16 storage for x/W/h/xl/p;
// f32 accumulate + f32 alpha/bias/output. Error budget: ~2^-10/product,
// ~3-5e-4/GEMM, well under 8.7e-3 threshold (at 1.95e-3 now).
#define HC 256
#define NEG_SLOPE 0.2f
#define SOFTMAX_EPS 1e-16f

typedef float floatx4 __attribute__((ext_vector_type(4)));
typedef _Float16 half8v __attribute__((ext_vector_type(8)));

// ---------------------------------------------------------------------------
// dtype sniffing: flags[0]=float-is-bf16, flags[1]=edge-index-is-int64.
// ---------------------------------------------------------------------------
__global__ void detect_kernel(const uint32_t* __restrict__ xw,
                              const uint32_t* __restrict__ ew,
                              int* __restrict__ flags) {
    __shared__ int cnt_bf16, cnt_odd_nz;
    const int t = threadIdx.x;
    if (t == 0) { cnt_bf16 = 0; cnt_odd_nz = 0; }
    __syncthreads();
    uint32_t w = xw[t];
    uint32_t ef = ((w & 0xFFFFu) >> 7) & 0xFFu;
    if (ef >= 90u && ef <= 135u) atomicAdd(&cnt_bf16, 1);
    if (t < 64 && ew[2 * t + 1] != 0u) atomicAdd(&cnt_odd_nz, 1);
    __syncthreads();
    if (t == 0) {
        flags[0] = (cnt_bf16 > 192) ? 1 : 0;
        flags[1] = (cnt_odd_nz == 0) ? 1 : 0;
    }
}

__device__ __forceinline__ float in_load(const void* p, int i, int is_bf16) {
    return is_bf16 ? (float)((const __bf16*)p)[i] : ((const float*)p)[i];
}

// six small f32 tensors (att_l1, att_r1, att_l2, att_r2, bp1, bp2)
__global__ void conv_small_kernel(const void* a0, float* o0, int n0,
                                  const void* a1, float* o1, int n1,
                                  const void* a2, float* o2, int n2,
                                  const void* a3, float* o3, int n3,
                                  const void* a4, float* o4, int n4,
                                  const void* a5, float* o5, int n5,
                                  const int* __restrict__ flags) {
    const int t = threadIdx.x;
    const int fb = flags[0];
    if (t < n0) o0[t] = in_load(a0, t, fb);
    if (t < n1) o1[t] = in_load(a1, t, fb);
    if (t < n2) o2[t] = in_load(a2, t, fb);
    if (t < n3) o3[t] = in_load(a3, t, fb);
    if (t < n4) o4[t] = in_load(a4, t, fb);
    if (t < n5) o5[t] = in_load(a5, t, fb);
}

// convert one tensor to fp16
__global__ void convh_kernel(const void* __restrict__ in, _Float16* __restrict__ out,
                             int n, const int* __restrict__ flags) {
    int i = blockIdx.x * blockDim.x + threadIdx.x;
    if (i < n) out[i] = (_Float16)in_load(in, i, flags[0]);
}

// convert the 4 weight matrices to fp16 in one launch
__global__ void conv4_kernel(const void* i0, _Float16* o0, int n0,
                             const void* i1, _Float16* o1, int n1,
                             const void* i2, _Float16* o2, int n2,
                             const void* i3, _Float16* o3, int n3,
                             const int* __restrict__ flags) {
    int idx = blockIdx.x * blockDim.x + threadIdx.x;
    const void* in;
    _Float16* po;
    int off = idx;
    if (off < n0)      { in = i0; po = o0; }
    else if ((off -= n0) < n1) { in = i1; po = o1; }
    else if ((off -= n1) < n2) { in = i2; po = o2; }
    else if ((off -= n2) < n3) { in = i3; po = o3; }
    else return;
    po[off] = (_Float16)in_load(in, off, flags[0]);
}

// ---------------------------------------------------------------------------
// GEMM: C[M,O] = A[M,KTEMP]@B[O,KTEMP]^T (+bias), fp16 operands, f32 acc.
// Block = 256 thr = 4 waves, M-tile 64; wave w owns O/4 cols (TW tiles).
// Per k-step: 4 A + TW B fragment loads, then 4*TW MFMAs. K fully unrolled.
// ALPHA (OTILES==16): fused per-row per-head att dots (f32).
// OMODE: 0=f32 out, 2=fp16 out.
// ---------------------------------------------------------------------------
template <int KTEMP, int OTILES, bool BIAS, bool ALPHA, int OMODE>
__global__ __launch_bounds__(256, 2) void gemm_bt(
    const _Float16* __restrict__ A, const _Float16* __restrict__ B,
    const float* __restrict__ bias,
    float* __restrict__ C, _Float16* __restrict__ Cf16,
    const float* __restrict__ attl, const float* __restrict__ attr,
    float* __restrict__ al, float* __restrict__ ar,
    int M) {
    static_assert(!ALPHA || OTILES == 16, "alpha fusion assumes O=256");
    constexpr int TW = OTILES / 4;
    constexpr int O = OTILES * 16;
    const int tid = threadIdx.x;
    const int lane = tid & 63;
    const int wave = tid >> 6;
    const int mbase = blockIdx.x * 64;
    const int l15 = lane & 15;
    const int q = lane >> 4;
    const int kq = q * 8;
    const int wc = wave * TW * 16;

    int arow[4];
#pragma unroll
    for (int rt = 0; rt < 4; rt++) arow[rt] = min(mbase + rt * 16 + l15, M - 1);

    floatx4 acc[4][TW];
#pragma unroll
    for (int rt = 0; rt < 4; rt++)
#pragma unroll
        for (int tt = 0; tt < TW; tt++) acc[rt][tt] = (floatx4){0.f, 0.f, 0.f, 0.f};

    constexpr int KSTEPS = KTEMP / 32;
#pragma unroll
    for (int ks = 0; ks < KSTEPS; ks++) {
        const int k0 = ks * 32;
        half8v af[4], bf[TW];
#pragma unroll
        for (int rt = 0; rt < 4; rt++)
            af[rt] = *(const half8v*)(A + (size_t)arow[rt] * KTEMP + k0 + kq);
#pragma unroll
        for (int tt = 0; tt < TW; tt++)
            bf[tt] = *(const half8v*)(B + (size_t)(wc + tt * 16 + l15) * KTEMP + k0 + kq);
#pragma unroll
        for (int rt = 0; rt < 4; rt++)
#pragma unroll
            for (int tt = 0; tt < TW; tt++)
                acc[rt][tt] = __builtin_amdgcn_mfma_f32_16x16x32_f16(af[rt], bf[tt], acc[rt][tt], 0, 0, 0);
    }

    // C/D layout: col = lane&15, row(in tile) = q*4 + reg  [m89/m91; dtype-indep]
    float aLp[4][4], aRp[4][4];
    if constexpr (ALPHA) {
#pragma unroll
        for (int rt = 0; rt < 4; rt++)
#pragma unroll
            for (int r = 0; r < 4; r++) { aLp[rt][r] = 0.f; aRp[rt][r] = 0.f; }
    }

#pragma unroll
    for (int rt = 0; rt < 4; rt++) {
        const int rb = mbase + rt * 16 + q * 4;
#pragma unroll
        for (int tt = 0; tt < TW; tt++) {
            const int gcol = wc + tt * 16 + l15;
            float atlv = 0.f, atrv = 0.f;
            if constexpr (ALPHA) { atlv = attl[gcol]; atrv = attr[gcol]; }
#pragma unroll
            for (int r = 0; r < 4; r++) {
                float v = acc[rt][tt][r];
                if constexpr (BIAS) v += bias[gcol];
                if constexpr (ALPHA) { aLp[rt][r] += v * atlv; aRp[rt][r] += v * atrv; }
                const int grow = rb + r;
                if (grow < M) {
                    if constexpr (OMODE == 2) {
                        Cf16[(size_t)grow * O + gcol] = (_Float16)v;
                    } else {
                        C[(size_t)grow * O + gcol] = v;
                    }
                }
            }
        }
    }

    if constexpr (ALPHA) {
        __shared__ float sAL[4][64], sAR[4][64];
#pragma unroll
        for (int rt = 0; rt < 4; rt++)
#pragma unroll
            for (int r = 0; r < 4; r++) {
                float vl = aLp[rt][r], vr = aRp[rt][r];
                vl += __shfl_xor(vl, 1); vl += __shfl_xor(vl, 2);
                vl += __shfl_xor(vl, 4); vl += __shfl_xor(vl, 8);
                vr += __shfl_xor(vr, 1); vr += __shfl_xor(vr, 2);
                vr += __shfl_xor(vr, 4); vr += __shfl_xor(vr, 8);
                if (l15 == 0) {
                    sAL[wave][rt * 16 + q * 4 + r] = vl;
                    sAR[wave][rt * 16 + q * 4 + r] = vr;
                }
            }
        __syncthreads();
        if (tid < 64) {
            const int grow = mbase + tid;
            if (grow < M) {
                al[2 * grow]     = sAL[0][tid] + sAL[1][tid];   // head 0 = waves 0,1
                al[2 * grow + 1] = sAL[2][tid] + sAL[3][tid];   // head 1 = waves 2,3
                ar[2 * grow]     = sAR[0][tid] + sAR[1][tid];
                ar[2 * grow + 1] = sAR[2][tid] + sAR[3][tid];
            }
        }
    }
}

// ---------------------------------------------------------------------------
// CSR build
// ---------------------------------------------------------------------------
__device__ __forceinline__ int edge_src(const int* ei, int E, int e, int is64) {
    return is64 ? ei[2 * (size_t)e] : ei[e];
}
__device__ __forceinline__ int edge_dst(const int* ei, int E, int e, int is64) {
    return is64 ? ei[2 * (size_t)E + 2 * (size_t)e] : ei[(size_t)E + e];
}

__global__ void count_kernel(const int* __restrict__ ei, int E,
                             const int* __restrict__ flags, int* __restrict__ counts) {
    int e = blockIdx.x * blockDim.x + threadIdx.x;
    if (e < E) atomicAdd(&counts[edge_dst(ei, E, e, flags[1])], 1);
}

__global__ __launch_bounds__(1024) void scan1_kernel(const int* __restrict__ counts,
                                                     int* __restrict__ incl,
                                                     int* __restrict__ bsum, int N) {
    __shared__ int tmp[1024];
    const int t = threadIdx.x;
    const int i = blockIdx.x * 1024 + t;
    int v = (i < N) ? counts[i] : 0;
    tmp[t] = v;
    __syncthreads();
    for (int off = 1; off < 1024; off <<= 1) {
        int x = (t >= off) ? tmp[t - off] : 0;
        __syncthreads();
        tmp[t] += x;
        __syncthreads();
    }
    if (i < N) incl[i] = tmp[t];
    if (t == 1023) bsum[blockIdx.x] = tmp[1023];
}

__global__ void scan2_kernel(const int* __restrict__ bsum, int* __restrict__ boffs,
                             int nb, int* __restrict__ row_ptr, int N) {
    if (threadIdx.x == 0) {
        int run = 0;
        for (int b = 0; b < nb; b++) { boffs[b] = run; run += bsum[b]; }
        row_ptr[N] = run;
    }
}

__global__ void scan3_kernel(const int* __restrict__ incl, const int* __restrict__ counts,
                             const int* __restrict__ boffs, int* __restrict__ row_ptr,
                             int* __restrict__ fill, int N) {
    int i = blockIdx.x * blockDim.x + threadIdx.x;
    if (i < N) {
        int v = boffs[i >> 10] + incl[i] - counts[i];
        row_ptr[i] = v;
        fill[i] = v;
    }
}

__global__ void scatter_kernel(const int* __restrict__ ei, int E,
                               const int* __restrict__ flags,
                               int* __restrict__ fill, int* __restrict__ esrc) {
    int e = blockIdx.x * blockDim.x + threadIdx.x;
    if (e < E) {
        int is64 = flags[1];
        int s = edge_src(ei, E, e, is64);
        int d = edge_dst(ei, E, e, is64);
        int pos = atomicAdd(&fill[d], 1);
        esrc[pos] = s;
    }
}

// ---------------------------------------------------------------------------
// Fused segment softmax + aggregation, wave-per-node, online softmax.
// Gather: half-wave per edge (16 B/lane), output fp16 h (single tensor).
// ---------------------------------------------------------------------------
__global__ __launch_bounds__(256) void agg_fused_kernel(
    const _Float16* __restrict__ xl,
    const float* __restrict__ al, const float* __restrict__ ar,
    const int* __restrict__ row_ptr, const int* __restrict__ esrc,
    _Float16* __restrict__ hout, int N) {
    const int wid = (blockIdx.x * 256 + threadIdx.x) >> 6;   // node id
    if (wid >= N) return;
    const int lane = threadIdx.x & 63;
    const int half = lane >> 5;          // which edge of the pair
    const int c8 = (lane & 31) * 8;      // my 8-column base
    const int hsel = c8 >> 7;            // head of my columns
    const int s0 = row_ptr[wid], e0 = row_ptr[wid + 1];
    const float ar0 = ar[2 * wid], ar1 = ar[2 * wid + 1];

    float acc[8];
#pragma unroll
    for (int c = 0; c < 8; c++) acc[c] = 0.f;
    float m0 = -INFINITY, m1 = -INFINITY, l0 = 0.f, l1 = 0.f;

    for (int base = s0; base < e0; base += 64) {
        const int n = min(64, e0 - base);
        int s = 0;
        float lg0 = -INFINITY, lg1 = -INFINITY;
        if (lane < n) {
            s = esrc[base + lane];
            float2 av = *(const float2*)(al + 2 * s);
            lg0 = av.x + ar0; lg0 = lg0 > 0.f ? lg0 : NEG_SLOPE * lg0;
            lg1 = av.y + ar1; lg1 = lg1 > 0.f ? lg1 : NEG_SLOPE * lg1;
        }
        float cm0 = lg0, cm1 = lg1;
#pragma unroll
        for (int off = 1; off < 64; off <<= 1) {
            cm0 = fmaxf(cm0, __shfl_xor(cm0, off));
            cm1 = fmaxf(cm1, __shfl_xor(cm1, off));
        }
        const float nm0 = fmaxf(m0, cm0), nm1 = fmaxf(m1, cm1);
        const float sc0 = __expf(m0 - nm0), sc1 = __expf(m1 - nm1);
        m0 = nm0; m1 = nm1;
        float p0 = 0.f, p1 = 0.f;
        if (lane < n) { p0 = __expf(lg0 - nm0); p1 = __expf(lg1 - nm1); }
        l0 = l0 * sc0 + p0;
        l1 = l1 * sc1 + p1;
        const float asc = hsel ? sc1 : sc0;
#pragma unroll
        for (int c = 0; c < 8; c++) acc[c] *= asc;

#pragma unroll 4
        for (int j = 0; j < n; j += 2) {
            const int jj = j + half;
            const float w0 = __shfl(p0, jj);
            const float w1 = __shfl(p1, jj);
            const int ss = __shfl(s, jj);
            if (jj < n) {
                const float wv = hsel ? w1 : w0;
                half8v xv = *(const half8v*)(xl + (size_t)ss * HC + c8);
#pragma unroll
                for (int c = 0; c < 8; c++) acc[c] += wv * (float)xv[c];
            }
        }
    }

#pragma unroll
    for (int off = 1; off < 64; off <<= 1) {
        l0 += __shfl_xor(l0, off);
        l1 += __shfl_xor(l1, off);
    }
    const float winv = 1.f / ((hsel ? l1 : l0) + SOFTMAX_EPS);

#pragma unroll
    for (int c = 0; c < 8; c++) {
        acc[c] += __shfl_xor(acc[c], 32);
        acc[c] = fmaxf(acc[c] * winv, 0.f);   // fused relu
    }
    if (half == 0) {
        half8v vo;
#pragma unroll
        for (int c = 0; c < 8; c++) vo[c] = (_Float16)acc[c];
        *(half8v*)(hout + (size_t)wid * HC + c8) = vo;
    }
}

// ---------------------------------------------------------------------------
extern "C" void kernel_launch(void* const* d_in, const int* in_sizes, int n_in,
                              void* d_out, int out_size, void* d_ws, size_t ws_size,
                              hipStream_t stream) {
    const int D = 128;
    const int N = in_sizes[0] / D;   // 50000
    const int E = in_sizes[1] / 2;   // 800000
    const int* ei = (const int*)d_in[1];

    char* w = (char*)d_ws;
    auto alloc = [&](size_t bytes) {
        void* p = w;
        w += (bytes + 255) & ~(size_t)255;
        return p;
    };
    int*      flags  = (int*)     alloc(256);
    _Float16* x16    = (_Float16*)alloc((size_t)N * D * 2);      // x; reused as p
    _Float16* W1f    = (_Float16*)alloc((size_t)in_sizes[2] * 2);
    _Float16* W2f    = (_Float16*)alloc((size_t)in_sizes[5] * 2);
    _Float16* Wp1f   = (_Float16*)alloc((size_t)in_sizes[8] * 2);
    _Float16* Wp2f   = (_Float16*)alloc((size_t)in_sizes[10] * 2);
    float*    atl1   = (float*)   alloc((size_t)in_sizes[3] * 4);
    float*    atr1   = (float*)   alloc((size_t)in_sizes[4] * 4);
    float*    atl2   = (float*)   alloc((size_t)in_sizes[6] * 4);
    float*    atr2   = (float*)   alloc((size_t)in_sizes[7] * 4);
    float*    bfp1   = (float*)   alloc((size_t)in_sizes[9] * 4);
    float*    bfp2   = (float*)   alloc((size_t)in_sizes[11] * 4);
    _Float16* xl16   = (_Float16*)alloc((size_t)N * HC * 2);     // 25.6 MB
    _Float16* h16    = (_Float16*)alloc((size_t)N * HC * 2);     // 25.6 MB
    float*    al     = (float*)   alloc((size_t)N * 2 * 4);
    float*    ar     = (float*)   alloc((size_t)N * 2 * 4);
    int*      counts = (int*)     alloc((size_t)N * 4);
    int*      incl   = (int*)     alloc((size_t)N * 4);
    int*      row_ptr= (int*)     alloc((size_t)(N + 1) * 4);
    int*      fill   = (int*)     alloc((size_t)N * 4);
    int*      bsum   = (int*)     alloc(1024);
    int*      boffs  = (int*)     alloc(1024);
    int*      esrc   = (int*)     alloc((size_t)E * 4);

    const int EB = (E + 255) / 256;
    const int GM = (N + 63) / 64;
    const int NB1024 = (N + 1023) / 1024;
    const int AGG_B = (N + 3) / 4;   // wave per node, 4 waves/block

    // 0. dtype sniff + canonicalize (fp16 operands, f32 att/bias)
    detect_kernel<<<1, 256, 0, stream>>>((const uint32_t*)d_in[0], (const uint32_t*)d_in[1], flags);
    conv_small_kernel<<<1, 256, 0, stream>>>(d_in[3], atl1, in_sizes[3],
                                             d_in[4], atr1, in_sizes[4],
                                             d_in[6], atl2, in_sizes[6],
                                             d_in[7], atr2, in_sizes[7],
                                             d_in[9], bfp1, in_sizes[9],
                                             d_in[11], bfp2, in_sizes[11], flags);
    convh_kernel<<<(in_sizes[0] + 255) / 256, 256, 0, stream>>>(d_in[0], x16, in_sizes[0], flags);
    {
        int nt = in_sizes[2] + in_sizes[5] + in_sizes[8] + in_sizes[10];
        conv4_kernel<<<(nt + 255) / 256, 256, 0, stream>>>(
            d_in[2], W1f, in_sizes[2],
            d_in[5], W2f, in_sizes[5],
            d_in[8], Wp1f, in_sizes[8],
            d_in[10], Wp2f, in_sizes[10], flags);
    }

    // 1. CSR build
    hipMemsetAsync(counts, 0, (size_t)N * 4, stream);
    count_kernel<<<EB, 256, 0, stream>>>(ei, E, flags, counts);
    scan1_kernel<<<NB1024, 1024, 0, stream>>>(counts, incl, bsum, N);
    scan2_kernel<<<1, 64, 0, stream>>>(bsum, boffs, NB1024, row_ptr, N);
    scan3_kernel<<<(N + 255) / 256, 256, 0, stream>>>(incl, counts, boffs, row_ptr, fill, N);
    scatter_kernel<<<EB, 256, 0, stream>>>(ei, E, flags, fill, esrc);

    // 2. GAT layer 1: xl16 = x@W1^T (alpha fused), K=128
    gemm_bt<128, 16, false, true, 2><<<GM, 256, 0, stream>>>(
        x16, W1f, nullptr, nullptr, xl16, atl1, atr1, al, ar, N);
    agg_fused_kernel<<<AGG_B, 256, 0, stream>>>(xl16, al, ar, row_ptr, esrc, h16, N);

    // 3. GAT layer 2: xl16 = h1@W2^T (alpha fused), K=256
    gemm_bt<256, 16, false, true, 2><<<GM, 256, 0, stream>>>(
        h16, W2f, nullptr, nullptr, xl16, atl2, atr2, al, ar, N);
    agg_fused_kernel<<<AGG_B, 256, 0, stream>>>(xl16, al, ar, row_ptr, esrc, h16, N);

    // 4. projections: p = h2@Wp1^T + bp1 (K=256, O=128, fp16 out into x16)
    gemm_bt<256, 8, true, false, 2><<<GM, 256, 0, stream>>>(
        h16, Wp1f, bfp1, nullptr, x16, nullptr, nullptr, nullptr, nullptr, N);
    // out = p@Wp2^T + bp2 (K=128, O=128) -> f32 d_out
    gemm_bt<128, 8, true, false, 0><<<GM, 256, 0, stream>>>(
        x16, Wp2f, bfp2, (float*)d_out, nullptr, nullptr, nullptr, nullptr, nullptr, N);
}